// Round 1
// baseline (372.815 us; speedup 1.0000x reference)
//
#include <hip/hip_runtime.h>

// Problem constants
#define BB 4
#define TT 2048
#define CC 768
#define HH 12
#define DD 64
#define MM (BB * TT)   // 8192 rows in the flattened [B*T, C] GEMMs

typedef __attribute__((ext_vector_type(8))) __bf16 bf16x8;
typedef __attribute__((ext_vector_type(4))) __bf16 bf16x4;
typedef __attribute__((ext_vector_type(4))) float f32x4;

// ---------------------------------------------------------------------------
// global -> LDS async copy, 16B per lane. LDS dest is WAVE-UNIFORM base;
// HW adds lane*16. Source address is per-lane (pre-swizzled for bank-conflict-
// free swizzled reads later; rule: swizzle BOTH source and read, LDS linear).
// ---------------------------------------------------------------------------
__device__ inline void gload16(const void* g, void* l) {
  __builtin_amdgcn_global_load_lds(
      (const __attribute__((address_space(1))) unsigned int*)g,
      (__attribute__((address_space(3))) unsigned int*)l, 16, 0, 0);
}

// ---------------------------------------------------------------------------
// fp32 -> bf16 cast kernels (vectorized: 2x float4 in, 1x 16B bf16x8 out)
// ---------------------------------------------------------------------------
__device__ inline void cast_body(const float* __restrict__ s, __bf16* __restrict__ d) {
  long i = ((long)blockIdx.x * 256 + threadIdx.x) * 8;
  f32x4 a = *(const f32x4*)(s + i);
  f32x4 b = *(const f32x4*)(s + i + 4);
  bf16x8 o;
  o[0] = (__bf16)a[0]; o[1] = (__bf16)a[1]; o[2] = (__bf16)a[2]; o[3] = (__bf16)a[3];
  o[4] = (__bf16)b[0]; o[5] = (__bf16)b[1]; o[6] = (__bf16)b[2]; o[7] = (__bf16)b[3];
  *(bf16x8*)(d + i) = o;
}

__global__ __launch_bounds__(256) void cast3(const float* __restrict__ s0, const float* __restrict__ s1,
                                             const float* __restrict__ s2,
                                             __bf16* d0, __bf16* d1, __bf16* d2) {
  const float* s = blockIdx.y == 0 ? s0 : blockIdx.y == 1 ? s1 : s2;
  __bf16* d = blockIdx.y == 0 ? d0 : blockIdx.y == 1 ? d1 : d2;
  cast_body(s, d);
}

__global__ __launch_bounds__(256) void cast4(const float* __restrict__ s0, const float* __restrict__ s1,
                                             const float* __restrict__ s2, const float* __restrict__ s3,
                                             __bf16* d0, __bf16* d1, __bf16* d2, __bf16* d3) {
  const float* s; __bf16* d;
  switch (blockIdx.y) {
    case 0: s = s0; d = d0; break;
    case 1: s = s1; d = d1; break;
    case 2: s = s2; d = d2; break;
    default: s = s3; d = d3; break;
  }
  cast_body(s, d);
}

// ---------------------------------------------------------------------------
// GEMM: C[m,n] = sum_k A[m,k] * W[n,k]   (x @ W^T, both bf16 row-major)
// Tile 128x128, BK=64, 256 threads (4 waves, 2x2 of 64x64), 16x16x32 MFMA.
// Staging via global_load_lds(16B) with XOR chunk swizzle (chunk ^= row&7) so
// the stride-128B ds_read_b128 fragment reads are ~2-way (free) not 16-way.
// MODE 0: write bf16 into [B,H,T,D] head layout (one of 3 tensors by z)
// MODE 1: write fp32 row-major [M,768] (final output projection)
// ---------------------------------------------------------------------------
template <int MODE>
__global__ __launch_bounds__(256) void gemm_proj(
    const __bf16* __restrict__ A0, const __bf16* __restrict__ A1, const __bf16* __restrict__ A2,
    const __bf16* __restrict__ W0, const __bf16* __restrict__ W1, const __bf16* __restrict__ W2,
    void* D0, void* D1, void* D2) {
  __shared__ __bf16 As[128 * 64];
  __shared__ __bf16 Bs[128 * 64];
  const int z = blockIdx.z;
  const __bf16* __restrict__ A = z == 0 ? A0 : z == 1 ? A1 : A2;
  const __bf16* __restrict__ W = z == 0 ? W0 : z == 1 ? W1 : W2;
  const int m0 = blockIdx.y * 128;
  const int n0 = blockIdx.x * 128;
  const int tid = threadIdx.x;
  const int wave = tid >> 6, lane = tid & 63;
  const int l15 = lane & 15, g = lane >> 4;
  const int wr = (wave >> 1) * 64, wc = (wave & 1) * 64;

  f32x4 acc[4][4] = {};

  for (int kt = 0; kt < CC / 64; ++kt) {
    __syncthreads();   // previous tile's reads done before overwrite
    const int k0 = kt * 64;
#pragma unroll
    for (int i = 0; i < 4; ++i) {
      const int r = wave + i * 4;          // 16 regions of 1KB per matrix
      const int L = r * 1024 + lane * 16;  // this lane's linear LDS byte
      const int row = L >> 7;              // 128B per row (64 bf16)
      const int sc = (L >> 4) & 7;
      const int gc = sc ^ (row & 7);       // inverse-swizzled source chunk
      gload16(A + (long)(m0 + row) * CC + k0 + gc * 8, &As[r * 512]);
      gload16(W + (long)(n0 + row) * CC + k0 + gc * 8, &Bs[r * 512]);
    }
    __syncthreads();   // implies vmcnt(0): staged data visible

#pragma unroll
    for (int kk = 0; kk < 2; ++kk) {
      bf16x8 af[4], bfr[4];
#pragma unroll
      for (int mi = 0; mi < 4; ++mi) {
        const int row = wr + mi * 16 + l15;
        const int c = (kk * 4 + g) ^ (row & 7);
        af[mi] = *(const bf16x8*)&As[row * 64 + c * 8];
      }
#pragma unroll
      for (int ni = 0; ni < 4; ++ni) {
        const int row = wc + ni * 16 + l15;
        const int c = (kk * 4 + g) ^ (row & 7);
        bfr[ni] = *(const bf16x8*)&Bs[row * 64 + c * 8];
      }
#pragma unroll
      for (int mi = 0; mi < 4; ++mi)
#pragma unroll
        for (int ni = 0; ni < 4; ++ni)
          acc[mi][ni] = __builtin_amdgcn_mfma_f32_16x16x32_bf16(af[mi], bfr[ni], acc[mi][ni], 0, 0, 0);
    }
  }

  // Epilogue. C/D layout: col = lane&15, row = (lane>>4)*4 + j (m89-verified).
#pragma unroll
  for (int mi = 0; mi < 4; ++mi) {
#pragma unroll
    for (int ni = 0; ni < 4; ++ni) {
#pragma unroll
      for (int j = 0; j < 4; ++j) {
        const int m = m0 + wr + mi * 16 + g * 4 + j;
        const int n = n0 + wc + ni * 16 + l15;
        const float v = acc[mi][ni][j];
        if (MODE == 0) {
          __bf16* Dst = (__bf16*)(z == 0 ? D0 : z == 1 ? D1 : D2);
          const int b = m >> 11, t = m & (TT - 1), h = n >> 6, d = n & 63;
          Dst[(((long)(b * HH + h)) * TT + t) * DD + d] = (__bf16)v;
        } else {
          float* Dst = (float*)D0;
          Dst[(long)m * CC + n] = v;
        }
      }
    }
  }
}

// ---------------------------------------------------------------------------
// Causal flash attention, bf16 MFMA, fp32 online softmax.
// Block = 256 thr (4 waves); block owns 64 q-rows of one (b,h); wave owns 16.
// KBLK = 64. Swapped QK^T: S^T = mfma(A=K, B=Q) so each lane holds one q-row's
// P values (16 of 64; rest in lanes l^16, l^32) -> softmax is in-lane + 2
// shfl_xor. P goes through padded per-wave LDS to get the A-operand layout
// for PV. K tile XOR-swizzled (row-major [64][128B] would be 16-way conflict).
// V staged transposed+swizzled so PV B-fragments are contiguous b128 reads.
// ---------------------------------------------------------------------------
__global__ __launch_bounds__(256) void attn_fwd(
    const __bf16* __restrict__ Qh, const __bf16* __restrict__ Kh,
    const __bf16* __restrict__ Vh, __bf16* __restrict__ Y) {
  __shared__ __bf16 Kl[64 * 64];        // [kv][d], swizzled: chunk ^= kv&7
  __shared__ __bf16 Vt[64 * 64];        // [d][kv], swizzled: chunk ^= d&7
  __shared__ __bf16 Pl[4][16 * 72];     // per-wave P: [q][64kv], stride 72 (144B, 16B-mult)

  const int bh = blockIdx.y;            // 0..47 = b*12+h
  const int q0 = blockIdx.x * 64;
  const int tid = threadIdx.x, wave = tid >> 6, lane = tid & 63;
  const int l15 = lane & 15, g = lane >> 4;
  const int qrow = q0 + wave * 16 + l15;           // this lane's softmax q-row

  const __bf16* qptr = Qh + ((long)bh * TT + qrow) * DD;
  bf16x8 qf[2];                                     // Q as B-operand: Q[l15][kk*32+g*8+j]
  qf[0] = *(const bf16x8*)(qptr + g * 8);
  qf[1] = *(const bf16x8*)(qptr + 32 + g * 8);

  f32x4 oacc[4] = {};                // O[q=g*4+j][d=ni*16+l15] per ni
  float m = -1e30f, lsum = 0.f;

  const int nt = q0 / 64 + 1;        // causal: only tiles with kv0 <= q0
  const __bf16* Kbase = Kh + (long)bh * TT * DD;
  const __bf16* Vbase = Vh + (long)bh * TT * DD;

  for (int kt = 0; kt < nt; ++kt) {
    const int kv0 = kt * 64;
    __syncthreads();                 // protect K/V LDS reuse

    // --- stage K: 8KB via async global_load_lds, pre-swizzled source ---
#pragma unroll
    for (int i = 0; i < 2; ++i) {
      const int r = wave + i * 4;
      const int L = r * 1024 + lane * 16;
      const int row = L >> 7, sc = (L >> 4) & 7, gc = sc ^ (row & 7);
      gload16(Kbase + (long)(kv0 + row) * DD + gc * 8, &Kl[r * 512]);
    }
    // --- stage V transposed: Vt[d][kv], swizzled on (d&7) ---
#pragma unroll
    for (int rr = 0; rr < 2; ++rr) {
      const int kv = (tid & 31) + rr * 32;
      const int dc = tid >> 5;       // 0..7 : d-chunk of 8
      bf16x8 vv = *(const bf16x8*)(Vbase + (long)(kv0 + kv) * DD + dc * 8);
#pragma unroll
      for (int j = 0; j < 8; ++j) {
        const int d = dc * 8 + j;
        const int byteoff = d * 128 + (((kv >> 3) ^ (d & 7)) << 4) + (kv & 7) * 2;
        *(__bf16*)((char*)Vt + byteoff) = vv[j];
      }
    }
    __syncthreads();

    // --- S^T = K * Q^T : sacc[mi] holds S[qrow][kv0+mi*16+g*4+j] ---
    f32x4 sacc[4] = {};
#pragma unroll
    for (int kk = 0; kk < 2; ++kk) {
#pragma unroll
      for (int mi = 0; mi < 4; ++mi) {
        const int row = mi * 16 + l15;                 // kv_local (A-operand row)
        const int c = (kk * 4 + g) ^ (row & 7);
        bf16x8 kf = *(const bf16x8*)&Kl[row * 64 + c * 8];
        sacc[mi] = __builtin_amdgcn_mfma_f32_16x16x32_bf16(kf, qf[kk], sacc[mi], 0, 0, 0);
      }
    }

    // --- online softmax (per-lane row; full row = this lane + l^16 + l^32) ---
    const bool maskt = (kt == nt - 1);                 // only diagonal tile masks
    float ps[4][4];
    float tmax = -1e30f;
#pragma unroll
    for (int mi = 0; mi < 4; ++mi) {
#pragma unroll
      for (int j = 0; j < 4; ++j) {
        float s = sacc[mi][j] * 0.125f;                // 1/sqrt(64)
        const int kv = kv0 + mi * 16 + g * 4 + j;
        if (maskt && kv > qrow) s = -1e30f;
        ps[mi][j] = s;
        tmax = fmaxf(tmax, s);
      }
    }
    tmax = fmaxf(tmax, __shfl_xor(tmax, 16));
    tmax = fmaxf(tmax, __shfl_xor(tmax, 32));
    const float mnew = fmaxf(m, tmax);
    const float corr = __expf(m - mnew);
    float rsum = 0.f;
#pragma unroll
    for (int mi = 0; mi < 4; ++mi) {
      bf16x4 pv;
#pragma unroll
      for (int j = 0; j < 4; ++j) {
        const float p = __expf(ps[mi][j] - mnew);
        rsum += p;
        pv[j] = (__bf16)p;
      }
      *(bf16x4*)&Pl[wave][l15 * 72 + mi * 16 + g * 4] = pv;   // P[q][kv] linear
    }
    rsum += __shfl_xor(rsum, 16);
    rsum += __shfl_xor(rsum, 32);
    lsum = lsum * corr + rsum;
    m = mnew;

    // rescale O: O-rows live at q=g*4+j, corr lives at lane l15=q -> shfl
#pragma unroll
    for (int j = 0; j < 4; ++j) {
      const float cj = __shfl(corr, g * 4 + j);
#pragma unroll
      for (int ni = 0; ni < 4; ++ni) oacc[ni][j] *= cj;
    }

    // --- PV: O += P * V ---
#pragma unroll
    for (int ks = 0; ks < 2; ++ks) {
      bf16x8 pa = *(const bf16x8*)&Pl[wave][l15 * 72 + ks * 32 + g * 8];
#pragma unroll
      for (int ni = 0; ni < 4; ++ni) {
        const int d = ni * 16 + l15;
        const int c = (ks * 4 + g) ^ (d & 7);
        bf16x8 vf = *(const bf16x8*)&Vt[d * 64 + c * 8];
        oacc[ni] = __builtin_amdgcn_mfma_f32_16x16x32_bf16(pa, vf, oacc[ni], 0, 0, 0);
      }
    }
  }

  // --- epilogue: normalize and write y in [B,T,C] bf16 ---
  const int b = bh / HH, h = bh % HH;
#pragma unroll
  for (int j = 0; j < 4; ++j) {
    const float lq = __shfl(lsum, g * 4 + j);
    const float inv = 1.0f / lq;
    const int q = q0 + wave * 16 + g * 4 + j;
#pragma unroll
    for (int ni = 0; ni < 4; ++ni) {
      const int col = h * DD + ni * 16 + l15;
      Y[((long)(b * TT + q)) * CC + col] = (__bf16)(oacc[ni][j] * inv);
    }
  }
}

// ---------------------------------------------------------------------------
// Host launcher
// ---------------------------------------------------------------------------
extern "C" void kernel_launch(void* const* d_in, const int* in_sizes, int n_in,
                              void* d_out, int out_size, void* d_ws, size_t ws_size,
                              hipStream_t stream) {
  (void)in_sizes; (void)n_in; (void)out_size; (void)ws_size;
  const float* q  = (const float*)d_in[0];
  const float* k  = (const float*)d_in[1];
  const float* v  = (const float*)d_in[2];
  const float* wq = (const float*)d_in[3];
  const float* wk = (const float*)d_in[4];
  const float* wv = (const float*)d_in[5];
  const float* wo = (const float*)d_in[6];

  char* ws = (char*)d_ws;
  const long SZX = (long)MM * CC * 2;      // 12,582,912 B per [8192,768] bf16
  const long SZW = (long)CC * CC * 2;      // 1,179,648 B per weight bf16
  __bf16* xq  = (__bf16*)(ws);
  __bf16* xk  = (__bf16*)(ws + SZX);
  __bf16* xv  = (__bf16*)(ws + 2 * SZX);
  __bf16* wwq = (__bf16*)(ws + 3 * SZX);
  __bf16* wwk = (__bf16*)(ws + 3 * SZX + SZW);
  __bf16* wwv = (__bf16*)(ws + 3 * SZX + 2 * SZW);
  __bf16* wwo = (__bf16*)(ws + 3 * SZX + 3 * SZW);
  __bf16* qh  = (__bf16*)(ws + 3 * SZX + 4 * SZW);
  __bf16* kh  = (__bf16*)(ws + 4 * SZX + 4 * SZW);
  __bf16* vh  = (__bf16*)(ws + 5 * SZX + 4 * SZW);
  __bf16* y   = xq;   // alias: xq is dead once projections are done

  // 1) casts
  cast3<<<dim3((MM * CC) / 2048, 3, 1), 256, 0, stream>>>(q, k, v, xq, xk, xv);
  cast4<<<dim3((CC * CC) / 2048, 4, 1), 256, 0, stream>>>(wq, wk, wv, wo, wwq, wwk, wwv, wwo);
  // 2) fused QKV projections -> head layout bf16
  gemm_proj<0><<<dim3(CC / 128, MM / 128, 3), 256, 0, stream>>>(xq, xk, xv, wwq, wwk, wwv, qh, kh, vh);
  // 3) causal flash attention -> y [B,T,C] bf16
  attn_fwd<<<dim3(TT / 64, BB * HH, 1), 256, 0, stream>>>(qh, kh, vh, y);
  // 4) output projection -> fp32 d_out
  gemm_proj<1><<<dim3(CC / 128, MM / 128, 1), 256, 0, stream>>>(y, y, y, wwo, wwo, wwo, d_out, d_out, d_out);
}

// Round 2
// 287.182 us; speedup vs baseline: 1.2982x; 1.2982x over previous
//
#include <hip/hip_runtime.h>

// Problem constants
#define BB 4
#define TT 2048
#define CC 768
#define HH 12
#define DD 64
#define MM (BB * TT)   // 8192 rows in the flattened [B*T, C] GEMMs

// 0.125 (1/sqrt(64)) * log2(e) folded into Q projection so softmax uses exp2 directly
#define QSCALE 0.18033688011112042f

typedef __attribute__((ext_vector_type(8))) __bf16 bf16x8;
typedef __attribute__((ext_vector_type(4))) __bf16 bf16x4;
typedef __attribute__((ext_vector_type(4))) float f32x4;

// ---------------------------------------------------------------------------
// global -> LDS async copy, 16B per lane. LDS dest is WAVE-UNIFORM base
// (HW adds lane*16); global source is per-lane (pre-swizzled so the
// XOR-swizzled ds_read side matches — both-sides-or-neither rule).
// ---------------------------------------------------------------------------
__device__ inline void gload16(const void* g, void* l) {
  __builtin_amdgcn_global_load_lds(
      (const __attribute__((address_space(1))) unsigned int*)g,
      (__attribute__((address_space(3))) unsigned int*)l, 16, 0, 0);
}

// ---------------------------------------------------------------------------
// fp32 -> bf16 cast kernels (vectorized: 2x float4 in, 1x 16B bf16x8 out)
// ---------------------------------------------------------------------------
__device__ inline void cast_body(const float* __restrict__ s, __bf16* __restrict__ d) {
  long i = ((long)blockIdx.x * 256 + threadIdx.x) * 8;
  f32x4 a = *(const f32x4*)(s + i);
  f32x4 b = *(const f32x4*)(s + i + 4);
  bf16x8 o;
  o[0] = (__bf16)a[0]; o[1] = (__bf16)a[1]; o[2] = (__bf16)a[2]; o[3] = (__bf16)a[3];
  o[4] = (__bf16)b[0]; o[5] = (__bf16)b[1]; o[6] = (__bf16)b[2]; o[7] = (__bf16)b[3];
  *(bf16x8*)(d + i) = o;
}

__global__ __launch_bounds__(256) void cast3(const float* __restrict__ s0, const float* __restrict__ s1,
                                             const float* __restrict__ s2,
                                             __bf16* d0, __bf16* d1, __bf16* d2) {
  const float* s = blockIdx.y == 0 ? s0 : blockIdx.y == 1 ? s1 : s2;
  __bf16* d = blockIdx.y == 0 ? d0 : blockIdx.y == 1 ? d1 : d2;
  cast_body(s, d);
}

__global__ __launch_bounds__(256) void cast4(const float* __restrict__ s0, const float* __restrict__ s1,
                                             const float* __restrict__ s2, const float* __restrict__ s3,
                                             __bf16* d0, __bf16* d1, __bf16* d2, __bf16* d3) {
  const float* s; __bf16* d;
  switch (blockIdx.y) {
    case 0: s = s0; d = d0; break;
    case 1: s = s1; d = d1; break;
    case 2: s = s2; d = d2; break;
    default: s = s3; d = d3; break;
  }
  cast_body(s, d);
}

// ---------------------------------------------------------------------------
// GEMM: C[m,n] = sum_k A[m,k] * W[n,k]   (x @ W^T, both bf16 row-major)
// Tile 128x128, BK=64, 256 threads (4 waves, 2x2 of 64x64), 16x16x32 MFMA.
// MODE 0: write bf16 head layouts: z==0 Q (pre-scaled by QSCALE) [bh][t][d],
//         z==1 K [bh][t][d], z==2 V TRANSPOSED [bh][d][t] (so attention can
//         stage V^T with the same swizzled gload16 path as K — no LDS
//         transpose in the attention kernel).
// MODE 1: write fp32 row-major [M,768] (final output projection)
// ---------------------------------------------------------------------------
template <int MODE>
__global__ __launch_bounds__(256) void gemm_proj(
    const __bf16* __restrict__ A0, const __bf16* __restrict__ A1, const __bf16* __restrict__ A2,
    const __bf16* __restrict__ W0, const __bf16* __restrict__ W1, const __bf16* __restrict__ W2,
    void* D0, void* D1, void* D2) {
  __shared__ __bf16 As[128 * 64];
  __shared__ __bf16 Bs[128 * 64];
  const int z = blockIdx.z;
  const __bf16* __restrict__ A = z == 0 ? A0 : z == 1 ? A1 : A2;
  const __bf16* __restrict__ W = z == 0 ? W0 : z == 1 ? W1 : W2;
  const int m0 = blockIdx.y * 128;
  const int n0 = blockIdx.x * 128;
  const int tid = threadIdx.x;
  const int wave = tid >> 6, lane = tid & 63;
  const int l15 = lane & 15, g = lane >> 4;
  const int wr = (wave >> 1) * 64, wc = (wave & 1) * 64;

  f32x4 acc[4][4] = {};

  for (int kt = 0; kt < CC / 64; ++kt) {
    __syncthreads();   // previous tile's reads done before overwrite
    const int k0 = kt * 64;
#pragma unroll
    for (int i = 0; i < 4; ++i) {
      const int r = wave + i * 4;          // 16 regions of 1KB per matrix
      const int L = r * 1024 + lane * 16;  // this lane's linear LDS byte
      const int row = L >> 7;              // 128B per row (64 bf16)
      const int sc = (L >> 4) & 7;
      const int gc = sc ^ (row & 7);       // inverse-swizzled source chunk
      gload16(A + (long)(m0 + row) * CC + k0 + gc * 8, &As[r * 512]);
      gload16(W + (long)(n0 + row) * CC + k0 + gc * 8, &Bs[r * 512]);
    }
    __syncthreads();   // implies vmcnt(0): staged data visible

#pragma unroll
    for (int kk = 0; kk < 2; ++kk) {
      bf16x8 af[4], bfr[4];
#pragma unroll
      for (int mi = 0; mi < 4; ++mi) {
        const int row = wr + mi * 16 + l15;
        const int c = (kk * 4 + g) ^ (row & 7);
        af[mi] = *(const bf16x8*)&As[row * 64 + c * 8];
      }
#pragma unroll
      for (int ni = 0; ni < 4; ++ni) {
        const int row = wc + ni * 16 + l15;
        const int c = (kk * 4 + g) ^ (row & 7);
        bfr[ni] = *(const bf16x8*)&Bs[row * 64 + c * 8];
      }
#pragma unroll
      for (int mi = 0; mi < 4; ++mi)
#pragma unroll
        for (int ni = 0; ni < 4; ++ni)
          acc[mi][ni] = __builtin_amdgcn_mfma_f32_16x16x32_bf16(af[mi], bfr[ni], acc[mi][ni], 0, 0, 0);
    }
  }

  // Epilogue. C/D layout: col = lane&15, row = (lane>>4)*4 + j (m89-verified).
#pragma unroll
  for (int mi = 0; mi < 4; ++mi) {
#pragma unroll
    for (int ni = 0; ni < 4; ++ni) {
#pragma unroll
      for (int j = 0; j < 4; ++j) {
        const int m = m0 + wr + mi * 16 + g * 4 + j;
        const int n = n0 + wc + ni * 16 + l15;
        float v = acc[mi][ni][j];
        if (MODE == 0) {
          __bf16* Dst = (__bf16*)(z == 0 ? D0 : z == 1 ? D1 : D2);
          const int b = m >> 11, t = m & (TT - 1), h = n >> 6, d = n & 63;
          if (z == 0) v *= QSCALE;                       // fold softmax scale into Q
          if (z == 2)                                    // V^T head-major [bh][d][t]
            Dst[(((long)(b * HH + h)) * DD + d) * TT + t] = (__bf16)v;
          else
            Dst[(((long)(b * HH + h)) * TT + t) * DD + d] = (__bf16)v;
        } else {
          float* Dst = (float*)D0;
          Dst[(long)m * CC + n] = v;
        }
      }
    }
  }
}

// ---------------------------------------------------------------------------
// Causal flash attention, bf16 MFMA, fp32 online softmax (base-2 domain).
// Block = 256 thr (4 waves). Balanced causal pairing: block a processes
// q-tiles {a, 31-a} sequentially -> every block does exactly 33 K-tile
// iterations; 768 blocks, 3/CU (41KB LDS), all co-resident, no tail.
// K and V^T double-buffered via async global_load_lds (swizzled source /
// swizzled read); ONE __syncthreads per tile; next tile's loads issued
// immediately after the barrier and hidden under compute.
// Swapped QK^T (S^T = mfma(K, Q)) keeps each q-row's P in one lane;
// softmax = in-lane fmax/exp2 + 2 shfl_xor. Defer-max (THR=8) skips the
// O-rescale on stable tiles.
// ---------------------------------------------------------------------------
__global__ __launch_bounds__(256) void attn_fwd(
    const __bf16* __restrict__ Qh, const __bf16* __restrict__ Kh,
    const __bf16* __restrict__ Vh, __bf16* __restrict__ Y) {
  __shared__ __bf16 Kl[2][64 * 64];     // [kv][d], chunk ^= kv&7
  __shared__ __bf16 Vl[2][64 * 64];     // V^T tile [d][kv], chunk ^= d&7
  __shared__ __bf16 Pl[4][16 * 72];     // per-wave P: [q][64kv], stride 72

  const int bh = blockIdx.y;            // 0..47 = b*12+h
  const int a = blockIdx.x;             // 0..15 -> q-tiles {a, 31-a}
  const int tid = threadIdx.x, wave = tid >> 6, lane = tid & 63;
  const int l15 = lane & 15, g = lane >> 4;
  const __bf16* Kbase = Kh + (long)bh * TT * DD;
  const __bf16* VTbase = Vh + (long)bh * DD * TT;   // [d][t]
  const int b = bh / HH, h = bh % HH;

  const int s_a = a + 1;                // tiles in phase 0
  const int total = 33;                 // (a+1) + (32-a)

  int qt = a;
  int qrow = qt * 64 + wave * 16 + l15;
  bf16x8 qf0, qf1;
  {
    const __bf16* qptr = Qh + ((long)bh * TT + qrow) * DD;
    qf0 = *(const bf16x8*)(qptr + g * 8);
    qf1 = *(const bf16x8*)(qptr + 32 + g * 8);
  }

  f32x4 oacc[4] = {};                   // O[q=g*4+j][d=ni*16+l15] per ni
  float m = -1e30f, lsum = 0.f;

  // prologue: stage tile 0 into buffer 0
#pragma unroll
  for (int i = 0; i < 2; ++i) {
    const int r = wave + i * 4;
    const int L = r * 1024 + lane * 16;
    const int row = L >> 7, sc = (L >> 4) & 7, gc = sc ^ (row & 7);
    gload16(Kbase + (long)row * DD + gc * 8, &Kl[0][r * 512]);
    gload16(VTbase + (long)row * TT + gc * 8, &Vl[0][r * 512]);
  }

  for (int s = 0; s < total; ++s) {
    __syncthreads();   // staged tile s visible; all waves done with tile s-1

    // --- issue async stage of tile s+1 into the other buffer ---
    if (s + 1 < total) {
      const int kt1 = (s + 1 >= s_a) ? (s + 1 - s_a) : (s + 1);
      const int kv1 = kt1 * 64;
      __bf16* Kd = Kl[(s + 1) & 1];
      __bf16* Vd = Vl[(s + 1) & 1];
#pragma unroll
      for (int i = 0; i < 2; ++i) {
        const int r = wave + i * 4;
        const int L = r * 1024 + lane * 16;
        const int row = L >> 7, sc = (L >> 4) & 7, gc = sc ^ (row & 7);
        gload16(Kbase + (long)(kv1 + row) * DD + gc * 8, Kd + r * 512);
        gload16(VTbase + (long)row * TT + kv1 + gc * 8, Vd + r * 512);
      }
    }

    // --- phase switch: write out q-tile a, start q-tile 31-a ---
    if (s == s_a) {
#pragma unroll
      for (int j = 0; j < 4; ++j) {
        const float lq = __shfl(lsum, g * 4 + j);
        const float inv = 1.0f / lq;
        const int q = qt * 64 + wave * 16 + g * 4 + j;
#pragma unroll
        for (int ni = 0; ni < 4; ++ni)
          Y[((long)(b * TT + q)) * CC + h * DD + ni * 16 + l15] = (__bf16)(oacc[ni][j] * inv);
      }
      qt = 31 - a;
      qrow = qt * 64 + wave * 16 + l15;
      const __bf16* qptr = Qh + ((long)bh * TT + qrow) * DD;
      qf0 = *(const bf16x8*)(qptr + g * 8);
      qf1 = *(const bf16x8*)(qptr + 32 + g * 8);
#pragma unroll
      for (int ni = 0; ni < 4; ++ni) oacc[ni] = (f32x4){0.f, 0.f, 0.f, 0.f};
      m = -1e30f; lsum = 0.f;
    }

    const int kt = (s >= s_a) ? (s - s_a) : s;
    const int kv0 = kt * 64;
    const bool maskt = (kt == qt);       // only the diagonal tile masks
    const __bf16* Kc = Kl[s & 1];
    const __bf16* Vc = Vl[s & 1];

    // --- S^T = K * Q^T : sacc[mi][j] = S[qrow][kv0+mi*16+g*4+j] (log2-scaled)
    f32x4 sacc[4] = {};
#pragma unroll
    for (int mi = 0; mi < 4; ++mi) {
      const int row = mi * 16 + l15;                 // kv_local
      const int c0 = g ^ (row & 7);
      const int c1 = (4 + g) ^ (row & 7);
      bf16x8 kfa = *(const bf16x8*)&Kc[row * 64 + c0 * 8];
      bf16x8 kfb = *(const bf16x8*)&Kc[row * 64 + c1 * 8];
      sacc[mi] = __builtin_amdgcn_mfma_f32_16x16x32_bf16(kfa, qf0, sacc[mi], 0, 0, 0);
      sacc[mi] = __builtin_amdgcn_mfma_f32_16x16x32_bf16(kfb, qf1, sacc[mi], 0, 0, 0);
    }

    // --- online softmax in exp2 domain ---
    float ps[4][4];
    float tmax = -1e30f;
#pragma unroll
    for (int mi = 0; mi < 4; ++mi) {
#pragma unroll
      for (int j = 0; j < 4; ++j) {
        float sv = sacc[mi][j];
        const int kv = kv0 + mi * 16 + g * 4 + j;
        if (maskt && kv > qrow) sv = -1e30f;
        ps[mi][j] = sv;
        tmax = fmaxf(tmax, sv);
      }
    }
    tmax = fmaxf(tmax, __shfl_xor(tmax, 16));
    tmax = fmaxf(tmax, __shfl_xor(tmax, 32));

    // defer-max: only rescale when some row's max grew by > 8 (P <= 2^8)
    if (!__all(tmax <= m + 8.0f)) {
      const float mnew = fmaxf(m, tmax);
      const float corr = exp2f(m - mnew);
#pragma unroll
      for (int j = 0; j < 4; ++j) {
        const float cj = __shfl(corr, g * 4 + j);
#pragma unroll
        for (int ni = 0; ni < 4; ++ni) oacc[ni][j] *= cj;
      }
      lsum *= corr;
      m = mnew;
    }

    float rsum = 0.f;
#pragma unroll
    for (int mi = 0; mi < 4; ++mi) {
      bf16x4 pv;
#pragma unroll
      for (int j = 0; j < 4; ++j) {
        const float p = exp2f(ps[mi][j] - m);
        rsum += p;
        pv[j] = (__bf16)p;
      }
      *(bf16x4*)&Pl[wave][l15 * 72 + mi * 16 + g * 4] = pv;   // P[q][kv] linear
    }
    rsum += __shfl_xor(rsum, 16);
    rsum += __shfl_xor(rsum, 32);
    lsum += rsum;

    // --- PV: O += P * V  (B-fragments straight from V^T tile, contiguous) ---
#pragma unroll
    for (int ks = 0; ks < 2; ++ks) {
      bf16x8 pa = *(const bf16x8*)&Pl[wave][l15 * 72 + ks * 32 + g * 8];
#pragma unroll
      for (int ni = 0; ni < 4; ++ni) {
        const int d = ni * 16 + l15;
        const int c = (ks * 4 + g) ^ (d & 7);
        bf16x8 vf = *(const bf16x8*)&Vc[d * 64 + c * 8];
        oacc[ni] = __builtin_amdgcn_mfma_f32_16x16x32_bf16(pa, vf, oacc[ni], 0, 0, 0);
      }
    }
  }

  // --- epilogue: write out q-tile 31-a ---
#pragma unroll
  for (int j = 0; j < 4; ++j) {
    const float lq = __shfl(lsum, g * 4 + j);
    const float inv = 1.0f / lq;
    const int q = qt * 64 + wave * 16 + g * 4 + j;
#pragma unroll
    for (int ni = 0; ni < 4; ++ni)
      Y[((long)(b * TT + q)) * CC + h * DD + ni * 16 + l15] = (__bf16)(oacc[ni][j] * inv);
  }
}

// ---------------------------------------------------------------------------
// Host launcher
// ---------------------------------------------------------------------------
extern "C" void kernel_launch(void* const* d_in, const int* in_sizes, int n_in,
                              void* d_out, int out_size, void* d_ws, size_t ws_size,
                              hipStream_t stream) {
  (void)in_sizes; (void)n_in; (void)out_size; (void)ws_size;
  const float* q  = (const float*)d_in[0];
  const float* k  = (const float*)d_in[1];
  const float* v  = (const float*)d_in[2];
  const float* wq = (const float*)d_in[3];
  const float* wk = (const float*)d_in[4];
  const float* wv = (const float*)d_in[5];
  const float* wo = (const float*)d_in[6];

  char* ws = (char*)d_ws;
  const long SZX = (long)MM * CC * 2;      // 12,582,912 B per [8192,768] bf16
  const long SZW = (long)CC * CC * 2;      // 1,179,648 B per weight bf16
  __bf16* xq  = (__bf16*)(ws);
  __bf16* xk  = (__bf16*)(ws + SZX);
  __bf16* xv  = (__bf16*)(ws + 2 * SZX);
  __bf16* wwq = (__bf16*)(ws + 3 * SZX);
  __bf16* wwk = (__bf16*)(ws + 3 * SZX + SZW);
  __bf16* wwv = (__bf16*)(ws + 3 * SZX + 2 * SZW);
  __bf16* wwo = (__bf16*)(ws + 3 * SZX + 3 * SZW);
  __bf16* qh  = (__bf16*)(ws + 3 * SZX + 4 * SZW);
  __bf16* kh  = (__bf16*)(ws + 4 * SZX + 4 * SZW);
  __bf16* vh  = (__bf16*)(ws + 5 * SZX + 4 * SZW);  // V^T head-major [bh][d][t]
  __bf16* y   = xq;   // alias: xq is dead once projections are done

  // 1) casts
  cast3<<<dim3((MM * CC) / 2048, 3, 1), 256, 0, stream>>>(q, k, v, xq, xk, xv);
  cast4<<<dim3((CC * CC) / 2048, 4, 1), 256, 0, stream>>>(wq, wk, wv, wo, wwq, wwk, wwv, wwo);
  // 2) fused QKV projections -> head layout bf16 (Q pre-scaled, V transposed)
  gemm_proj<0><<<dim3(CC / 128, MM / 128, 3), 256, 0, stream>>>(xq, xk, xv, wwq, wwk, wwv, qh, kh, vh);
  // 3) causal flash attention (balanced pairing) -> y [B,T,C] bf16
  attn_fwd<<<dim3(TT / 128, BB * HH, 1), 256, 0, stream>>>(qh, kh, vh, y);
  // 4) output projection -> fp32 d_out
  gemm_proj<1><<<dim3(CC / 128, MM / 128, 1), 256, 0, stream>>>(y, y, y, wwo, wwo, wwo, d_out, d_out, d_out);
}

// Round 3
// 261.916 us; speedup vs baseline: 1.4234x; 1.0965x over previous
//
#include <hip/hip_runtime.h>

// Problem constants
#define BB 4
#define TT 2048
#define CC 768
#define HH 12
#define DD 64
#define MM (BB * TT)   // 8192 rows in the flattened [B*T, C] GEMMs

// 0.125 (1/sqrt(64)) * log2(e) folded into Q projection so softmax uses exp2 directly
#define QSCALE 0.18033688011112042f

typedef __attribute__((ext_vector_type(8))) __bf16 bf16x8;
typedef __attribute__((ext_vector_type(4))) __bf16 bf16x4;
typedef __attribute__((ext_vector_type(4))) float f32x4;

// ---------------------------------------------------------------------------
// global -> LDS async copy, 16B per lane. LDS dest is WAVE-UNIFORM base
// (HW adds lane*16); global source is per-lane (pre-swizzled so the
// XOR-swizzled ds_read side matches — both-sides-or-neither rule).
// ---------------------------------------------------------------------------
__device__ inline void gload16(const void* g, void* l) {
  __builtin_amdgcn_global_load_lds(
      (const __attribute__((address_space(1))) unsigned int*)g,
      (__attribute__((address_space(3))) unsigned int*)l, 16, 0, 0);
}

// ---------------------------------------------------------------------------
// fp32 -> bf16 cast kernels (vectorized: 2x float4 in, 1x 16B bf16x8 out)
// ---------------------------------------------------------------------------
__device__ inline void cast_body(const float* __restrict__ s, __bf16* __restrict__ d) {
  long i = ((long)blockIdx.x * 256 + threadIdx.x) * 8;
  f32x4 a = *(const f32x4*)(s + i);
  f32x4 b = *(const f32x4*)(s + i + 4);
  bf16x8 o;
  o[0] = (__bf16)a[0]; o[1] = (__bf16)a[1]; o[2] = (__bf16)a[2]; o[3] = (__bf16)a[3];
  o[4] = (__bf16)b[0]; o[5] = (__bf16)b[1]; o[6] = (__bf16)b[2]; o[7] = (__bf16)b[3];
  *(bf16x8*)(d + i) = o;
}

__global__ __launch_bounds__(256) void cast3(const float* __restrict__ s0, const float* __restrict__ s1,
                                             const float* __restrict__ s2,
                                             __bf16* d0, __bf16* d1, __bf16* d2) {
  const float* s = blockIdx.y == 0 ? s0 : blockIdx.y == 1 ? s1 : s2;
  __bf16* d = blockIdx.y == 0 ? d0 : blockIdx.y == 1 ? d1 : d2;
  cast_body(s, d);
}

__global__ __launch_bounds__(256) void cast4(const float* __restrict__ s0, const float* __restrict__ s1,
                                             const float* __restrict__ s2, const float* __restrict__ s3,
                                             __bf16* d0, __bf16* d1, __bf16* d2, __bf16* d3) {
  const float* s; __bf16* d;
  switch (blockIdx.y) {
    case 0: s = s0; d = d0; break;
    case 1: s = s1; d = d1; break;
    case 2: s = s2; d = d2; break;
    default: s = s3; d = d3; break;
  }
  cast_body(s, d);
}

// ---------------------------------------------------------------------------
// GEMM helpers
// ---------------------------------------------------------------------------
__device__ inline void stage_tile(const __bf16* __restrict__ A, const __bf16* __restrict__ W,
                                  long m0, long n0, int k0,
                                  __bf16* As, __bf16* Bs, int wave, int lane) {
#pragma unroll
  for (int i = 0; i < 4; ++i) {
    const int r = wave + i * 4;          // 16 regions of 1KB per matrix
    const int L = r * 1024 + lane * 16;  // this lane's linear LDS byte
    const int row = L >> 7;              // 128B per row (64 bf16)
    const int sc = (L >> 4) & 7;
    const int gc = sc ^ (row & 7);       // inverse-swizzled source chunk
    gload16(A + (m0 + row) * CC + k0 + gc * 8, As + r * 512);
    gload16(W + (n0 + row) * CC + k0 + gc * 8, Bs + r * 512);
  }
}

__device__ inline void compute_tile(const __bf16* As, const __bf16* Bs, f32x4 (&acc)[4][4],
                                    int wr, int wc, int l15, int g) {
#pragma unroll
  for (int kk = 0; kk < 2; ++kk) {
    bf16x8 af[4], bfr[4];
#pragma unroll
    for (int mi = 0; mi < 4; ++mi) {
      const int row = wr + mi * 16 + l15;
      const int c = (kk * 4 + g) ^ (row & 7);
      af[mi] = *(const bf16x8*)&As[row * 64 + c * 8];
    }
#pragma unroll
    for (int ni = 0; ni < 4; ++ni) {
      const int row = wc + ni * 16 + l15;
      const int c = (kk * 4 + g) ^ (row & 7);
      bfr[ni] = *(const bf16x8*)&Bs[row * 64 + c * 8];
    }
#pragma unroll
    for (int mi = 0; mi < 4; ++mi)
#pragma unroll
      for (int ni = 0; ni < 4; ++ni)
        acc[mi][ni] = __builtin_amdgcn_mfma_f32_16x16x32_bf16(af[mi], bfr[ni], acc[mi][ni], 0, 0, 0);
  }
}

// ---------------------------------------------------------------------------
// GEMM: C[m,n] = sum_k A[m,k] * W[n,k]   (x @ W^T, both bf16 row-major)
// Tile 128x128, BK=64, 256 threads (4 waves, 2x2 of 64x64), 16x16x32 MFMA.
// 2-phase double-buffered K-loop: stage(t+1) issued BEFORE compute(t); one
// __syncthreads per iter (its vmcnt(0) drain overlaps the compute phase).
// Epilogue restages the C-tile through swizzled LDS for coalesced vector
// stores (the old 64-scalar-2B-store scatter was the write bottleneck).
// MODE 0: bf16 head layouts: z==0 Q (pre-scaled) [bh][t][d], z==1 K [bh][t][d],
//         z==2 V TRANSPOSED [bh][d][t].
// MODE 1: fp32 row-major [M,768] (final output projection)
// ---------------------------------------------------------------------------
template <int MODE>
__global__ __launch_bounds__(256) void gemm_proj(
    const __bf16* __restrict__ A0, const __bf16* __restrict__ A1, const __bf16* __restrict__ A2,
    const __bf16* __restrict__ W0, const __bf16* __restrict__ W1, const __bf16* __restrict__ W2,
    void* D0, void* D1, void* D2) {
  __shared__ __align__(16) char smem[65536];
  __bf16* As0 = (__bf16*)smem;                    // 16 KB
  __bf16* Bs0 = (__bf16*)(smem + 16384);
  __bf16* As1 = (__bf16*)(smem + 32768);
  __bf16* Bs1 = (__bf16*)(smem + 49152);

  const int z = blockIdx.z;
  const __bf16* __restrict__ A = z == 0 ? A0 : z == 1 ? A1 : A2;
  const __bf16* __restrict__ W = z == 0 ? W0 : z == 1 ? W1 : W2;
  const long m0 = blockIdx.y * 128;
  const long n0 = blockIdx.x * 128;
  const int tid = threadIdx.x;
  const int wave = tid >> 6, lane = tid & 63;
  const int l15 = lane & 15, g = lane >> 4;
  const int wr = (wave >> 1) * 64, wc = (wave & 1) * 64;

  f32x4 acc[4][4] = {};

  stage_tile(A, W, m0, n0, 0, As0, Bs0, wave, lane);
  __syncthreads();
  for (int kt = 0; kt < 12; kt += 2) {
    stage_tile(A, W, m0, n0, (kt + 1) * 64, As1, Bs1, wave, lane);
    compute_tile(As0, Bs0, acc, wr, wc, l15, g);
    __syncthreads();
    if (kt + 2 < 12) stage_tile(A, W, m0, n0, (kt + 2) * 64, As0, Bs0, wave, lane);
    compute_tile(As1, Bs1, acc, wr, wc, l15, g);
    __syncthreads();
  }

  // ---- epilogue via LDS restage, two passes of a 64x128 half-tile ----
  // C/D frag layout: col = lane&15, row = (lane>>4)*4 + j (m89-verified).
  const int b = (int)(m0 >> 11);
  const int t0 = (int)(m0 & (TT - 1));
  if (MODE == 1) {
    float* Ef = (float*)smem;                     // [64][128] f32, 32 KB
    float* Dst = (float*)D0;
    for (int p = 0; p < 2; ++p) {
      if (p) __syncthreads();
      if ((wr >> 6) == p) {
#pragma unroll
        for (int mi = 0; mi < 4; ++mi)
#pragma unroll
          for (int ni = 0; ni < 4; ++ni)
#pragma unroll
            for (int j = 0; j < 4; ++j) {
              const int ml = mi * 16 + g * 4 + j;           // 0..63
              const int n = wc + ni * 16 + l15;             // 0..127
              *(float*)((char*)Ef + ml * 512 + ((n * 4) ^ (((ml >> 2) & 7) << 4))) = acc[mi][ni][j];
            }
      }
      __syncthreads();
#pragma unroll
      for (int sw = 0; sw < 8; ++sw) {
        const int r = sw * 8 + (tid >> 5);
        const int c = (tid & 31) * 4;
        f32x4 vv = *(const f32x4*)((char*)Ef + r * 512 + ((c * 4) ^ (((r >> 2) & 7) << 4)));
        *(f32x4*)&Dst[(m0 + p * 64 + r) * CC + n0 + c] = vv;
      }
    }
  } else {
    __bf16* Eh = (__bf16*)smem;                   // [64][128] bf16, 16 KB
    __bf16* Dst = (__bf16*)(z == 0 ? D0 : z == 1 ? D1 : D2);
    for (int p = 0; p < 2; ++p) {
      if (p) __syncthreads();
      if (z != 2) {
        if ((wr >> 6) == p) {
#pragma unroll
          for (int mi = 0; mi < 4; ++mi)
#pragma unroll
            for (int ni = 0; ni < 4; ++ni)
#pragma unroll
              for (int j = 0; j < 4; ++j) {
                const int ml = mi * 16 + g * 4 + j;
                const int n = wc + ni * 16 + l15;
                float v = acc[mi][ni][j];
                if (z == 0) v *= QSCALE;
                *(__bf16*)((char*)Eh + ml * 256 + ((n * 2) ^ (((ml >> 2) & 7) << 4))) = (__bf16)v;
              }
        }
      } else {
        if ((wc >> 6) == p) {
#pragma unroll
          for (int mi = 0; mi < 4; ++mi)
#pragma unroll
            for (int ni = 0; ni < 4; ++ni)
#pragma unroll
              for (int j = 0; j < 4; ++j) {
                const int nl = ni * 16 + l15;                // 0..63 (d within half)
                const int mm = wr + mi * 16 + g * 4 + j;     // 0..127 (t)
                *(__bf16*)((char*)Eh + nl * 256 + ((mm * 2) ^ ((nl & 7) << 4))) = (__bf16)acc[mi][ni][j];
              }
        }
      }
      __syncthreads();
#pragma unroll
      for (int sw = 0; sw < 4; ++sw) {
        const int r = sw * 16 + (tid >> 4);
        const int c = (tid & 15) * 8;
        if (z != 2) {
          bf16x8 vv = *(const bf16x8*)((char*)Eh + r * 256 + ((c * 2) ^ (((r >> 2) & 7) << 4)));
          const int t = t0 + p * 64 + r;
          const int n = (int)n0 + c;
          const int h = n >> 6, d = n & 63;
          *(bf16x8*)&Dst[(((long)(b * HH + h)) * TT + t) * DD + d] = vv;
        } else {
          bf16x8 vv = *(const bf16x8*)((char*)Eh + r * 256 + ((c * 2) ^ ((r & 7) << 4)));
          const int n = (int)n0 + p * 64 + r;                // head-dim index
          const int h = n >> 6, d = n & 63;
          *(bf16x8*)&Dst[(((long)(b * HH + h)) * DD + d) * TT + t0 + c] = vv;
        }
      }
    }
  }
}

// ---------------------------------------------------------------------------
// Causal flash attention, bf16 MFMA, fp32 online softmax (base-2 domain).
// Block = 256 thr (4 waves). Balanced causal pairing: block a processes
// q-tiles {a, 31-a} -> every block does exactly 33 K-tile iterations.
// K and V^T double-buffered via async global_load_lds; ONE __syncthreads per
// tile; next tile's loads issued right after the barrier, hidden by compute.
// Swapped QK^T (S^T = mfma(K, Q)) keeps each q-row's P in one lane.
// Steady-state softmax has ZERO cross-lane ops: per-lane partial lsum
// (combined across the 4 sibling lanes only at epilogue) and row-max m
// updated only when the defer-max trigger fires (rare; first tile always).
// ---------------------------------------------------------------------------
__global__ __launch_bounds__(256) void attn_fwd(
    const __bf16* __restrict__ Qh, const __bf16* __restrict__ Kh,
    const __bf16* __restrict__ Vh, __bf16* __restrict__ Y) {
  __shared__ __bf16 Kl[2][64 * 64];     // [kv][d], chunk ^= kv&7
  __shared__ __bf16 Vl[2][64 * 64];     // V^T tile [d][kv], chunk ^= d&7
  __shared__ __bf16 Pl[4][16 * 64];     // per-wave P [q][64kv], chunk ^= q&7
  // total LDS = 16K + 16K + 8K = 40960 B

  const int bh = blockIdx.y;            // 0..47 = b*12+h
  const int a = blockIdx.x;             // 0..15 -> q-tiles {a, 31-a}
  const int tid = threadIdx.x, wave = tid >> 6, lane = tid & 63;
  const int l15 = lane & 15, g = lane >> 4;
  const __bf16* Kbase = Kh + (long)bh * TT * DD;
  const __bf16* VTbase = Vh + (long)bh * DD * TT;   // [d][t]
  const int b = bh / HH, h = bh % HH;
  char* Pb = (char*)&Pl[wave][0];

  const int s_a = a + 1;                // tiles in phase 0
  const int total = 33;                 // (a+1) + (32-a)

  int qt = a;
  int qrow = qt * 64 + wave * 16 + l15;
  bf16x8 qf0, qf1;
  {
    const __bf16* qptr = Qh + ((long)bh * TT + qrow) * DD;
    qf0 = *(const bf16x8*)(qptr + g * 8);
    qf1 = *(const bf16x8*)(qptr + 32 + g * 8);
  }

  f32x4 oacc[4] = {};                   // O[q=g*4+j][d=ni*16+l15] per ni
  float m = -1e30f, lsum = 0.f;         // lsum is PER-LANE partial

  // prologue: stage tile 0 into buffer 0
#pragma unroll
  for (int i = 0; i < 2; ++i) {
    const int r = wave + i * 4;
    const int L = r * 1024 + lane * 16;
    const int row = L >> 7, sc = (L >> 4) & 7, gc = sc ^ (row & 7);
    gload16(Kbase + (long)row * DD + gc * 8, &Kl[0][r * 512]);
    gload16(VTbase + (long)row * TT + gc * 8, &Vl[0][r * 512]);
  }

  for (int s = 0; s < total; ++s) {
    __syncthreads();   // staged tile s visible; all waves done with tile s-1

    // --- issue async stage of tile s+1 into the other buffer ---
    if (s + 1 < total) {
      const int kt1 = (s + 1 >= s_a) ? (s + 1 - s_a) : (s + 1);
      const int kv1 = kt1 * 64;
      __bf16* Kd = Kl[(s + 1) & 1];
      __bf16* Vd = Vl[(s + 1) & 1];
#pragma unroll
      for (int i = 0; i < 2; ++i) {
        const int r = wave + i * 4;
        const int L = r * 1024 + lane * 16;
        const int row = L >> 7, sc = (L >> 4) & 7, gc = sc ^ (row & 7);
        gload16(Kbase + (long)(kv1 + row) * DD + gc * 8, Kd + r * 512);
        gload16(VTbase + (long)row * TT + kv1 + gc * 8, Vd + r * 512);
      }
    }

    // --- phase switch: write out q-tile a, start q-tile 31-a ---
    if (s == s_a) {
      float lrow = lsum + __shfl_xor(lsum, 16);
      lrow += __shfl_xor(lrow, 32);
#pragma unroll
      for (int j = 0; j < 4; ++j) {
        const float inv = 1.0f / __shfl(lrow, g * 4 + j);
        const int q = qt * 64 + wave * 16 + g * 4 + j;
#pragma unroll
        for (int ni = 0; ni < 4; ++ni)
          Y[((long)(b * TT + q)) * CC + h * DD + ni * 16 + l15] = (__bf16)(oacc[ni][j] * inv);
      }
      qt = 31 - a;
      qrow = qt * 64 + wave * 16 + l15;
      const __bf16* qptr = Qh + ((long)bh * TT + qrow) * DD;
      qf0 = *(const bf16x8*)(qptr + g * 8);
      qf1 = *(const bf16x8*)(qptr + 32 + g * 8);
#pragma unroll
      for (int ni = 0; ni < 4; ++ni) oacc[ni] = (f32x4){0.f, 0.f, 0.f, 0.f};
      m = -1e30f; lsum = 0.f;
    }

    const int kt = (s >= s_a) ? (s - s_a) : s;
    const int kv0 = kt * 64;
    const bool maskt = (kt == qt);       // only the diagonal tile masks
    const __bf16* Kc = Kl[s & 1];
    const __bf16* Vc = Vl[s & 1];

    // --- S^T = K * Q^T : sacc[mi][j] = S[qrow][kv0+mi*16+g*4+j] (log2-scaled)
    f32x4 sacc[4] = {};
#pragma unroll
    for (int mi = 0; mi < 4; ++mi) {
      const int row = mi * 16 + l15;                 // kv_local
      const int c0 = g ^ (row & 7);
      const int c1 = (4 + g) ^ (row & 7);
      bf16x8 kfa = *(const bf16x8*)&Kc[row * 64 + c0 * 8];
      bf16x8 kfb = *(const bf16x8*)&Kc[row * 64 + c1 * 8];
      sacc[mi] = __builtin_amdgcn_mfma_f32_16x16x32_bf16(kfa, qf0, sacc[mi], 0, 0, 0);
      sacc[mi] = __builtin_amdgcn_mfma_f32_16x16x32_bf16(kfb, qf1, sacc[mi], 0, 0, 0);
    }

    // --- online softmax, steady-state shuffle-free ---
    float ps[4][4];
    float tmax = -3e30f;
    if (maskt) {
#pragma unroll
      for (int mi = 0; mi < 4; ++mi)
#pragma unroll
        for (int j = 0; j < 4; ++j) {
          float sv = sacc[mi][j];
          const int kv = kv0 + mi * 16 + g * 4 + j;
          if (kv > qrow) sv = -3e30f;
          ps[mi][j] = sv;
          tmax = fmaxf(tmax, sv);
        }
    } else {
#pragma unroll
      for (int mi = 0; mi < 4; ++mi)
#pragma unroll
        for (int j = 0; j < 4; ++j) {
          const float sv = sacc[mi][j];
          ps[mi][j] = sv;
          tmax = fmaxf(tmax, sv);
        }
    }

    // defer-max: only rescale when some row's max grew by > 8 (P <= 2^8)
    if (!__all(tmax <= m + 8.0f)) {
      float full = fmaxf(tmax, __shfl_xor(tmax, 16));
      full = fmaxf(full, __shfl_xor(full, 32));
      const float mnew = fmaxf(m, full);
      const float corr = exp2f(m - mnew);    // this lane's row (l15) corr
#pragma unroll
      for (int j = 0; j < 4; ++j) {
        const float cj = __shfl(corr, g * 4 + j);
#pragma unroll
        for (int ni = 0; ni < 4; ++ni) oacc[ni][j] *= cj;
      }
      lsum *= corr;
      m = mnew;
    }

#pragma unroll
    for (int mi = 0; mi < 4; ++mi) {
      bf16x4 pv;
#pragma unroll
      for (int j = 0; j < 4; ++j) {
        const float p = exp2f(ps[mi][j] - m);
        lsum += p;
        pv[j] = (__bf16)p;
      }
      // P [q=l15][kv], stride 64, chunk ^= l15&7
      *(bf16x4*)(Pb + l15 * 128 + ((mi * 32 + g * 8) ^ ((l15 & 7) << 4))) = pv;
    }

    // --- PV: O += P * V  (B-fragments straight from V^T tile) ---
#pragma unroll
    for (int ks = 0; ks < 2; ++ks) {
      bf16x8 pa = *(const bf16x8*)(Pb + l15 * 128 + ((ks * 64 + g * 16) ^ ((l15 & 7) << 4)));
#pragma unroll
      for (int ni = 0; ni < 4; ++ni) {
        const int d = ni * 16 + l15;
        const int c = (ks * 4 + g) ^ (d & 7);
        bf16x8 vf = *(const bf16x8*)&Vc[d * 64 + c * 8];
        oacc[ni] = __builtin_amdgcn_mfma_f32_16x16x32_bf16(pa, vf, oacc[ni], 0, 0, 0);
      }
    }
  }

  // --- epilogue: write out q-tile 31-a ---
  {
    float lrow = lsum + __shfl_xor(lsum, 16);
    lrow += __shfl_xor(lrow, 32);
#pragma unroll
    for (int j = 0; j < 4; ++j) {
      const float inv = 1.0f / __shfl(lrow, g * 4 + j);
      const int q = qt * 64 + wave * 16 + g * 4 + j;
#pragma unroll
      for (int ni = 0; ni < 4; ++ni)
        Y[((long)(b * TT + q)) * CC + h * DD + ni * 16 + l15] = (__bf16)(oacc[ni][j] * inv);
    }
  }
}

// ---------------------------------------------------------------------------
// Host launcher
// ---------------------------------------------------------------------------
extern "C" void kernel_launch(void* const* d_in, const int* in_sizes, int n_in,
                              void* d_out, int out_size, void* d_ws, size_t ws_size,
                              hipStream_t stream) {
  (void)in_sizes; (void)n_in; (void)out_size; (void)ws_size;
  const float* q  = (const float*)d_in[0];
  const float* k  = (const float*)d_in[1];
  const float* v  = (const float*)d_in[2];
  const float* wq = (const float*)d_in[3];
  const float* wk = (const float*)d_in[4];
  const float* wv = (const float*)d_in[5];
  const float* wo = (const float*)d_in[6];

  char* ws = (char*)d_ws;
  const long SZX = (long)MM * CC * 2;      // 12,582,912 B per [8192,768] bf16
  const long SZW = (long)CC * CC * 2;      // 1,179,648 B per weight bf16
  __bf16* xq  = (__bf16*)(ws);
  __bf16* xk  = (__bf16*)(ws + SZX);
  __bf16* xv  = (__bf16*)(ws + 2 * SZX);
  __bf16* wwq = (__bf16*)(ws + 3 * SZX);
  __bf16* wwk = (__bf16*)(ws + 3 * SZX + SZW);
  __bf16* wwv = (__bf16*)(ws + 3 * SZX + 2 * SZW);
  __bf16* wwo = (__bf16*)(ws + 3 * SZX + 3 * SZW);
  __bf16* qh  = (__bf16*)(ws + 3 * SZX + 4 * SZW);
  __bf16* kh  = (__bf16*)(ws + 4 * SZX + 4 * SZW);
  __bf16* vh  = (__bf16*)(ws + 5 * SZX + 4 * SZW);  // V^T head-major [bh][d][t]
  __bf16* y   = xq;   // alias: xq is dead once projections are done

  // 1) casts
  cast3<<<dim3((MM * CC) / 2048, 3, 1), 256, 0, stream>>>(q, k, v, xq, xk, xv);
  cast4<<<dim3((CC * CC) / 2048, 4, 1), 256, 0, stream>>>(wq, wk, wv, wo, wwq, wwk, wwv, wwo);
  // 2) fused QKV projections -> head layout bf16 (Q pre-scaled, V transposed)
  gemm_proj<0><<<dim3(CC / 128, MM / 128, 3), 256, 0, stream>>>(xq, xk, xv, wwq, wwk, wwv, qh, kh, vh);
  // 3) causal flash attention (balanced pairing) -> y [B,T,C] bf16
  attn_fwd<<<dim3(TT / 128, BB * HH, 1), 256, 0, stream>>>(qh, kh, vh, y);
  // 4) output projection -> fp32 d_out
  gemm_proj<1><<<dim3(CC / 128, MM / 128, 1), 256, 0, stream>>>(y, y, y, wwo, wwo, wwo, d_out, d_out, d_out);
}

// Round 5
// 240.721 us; speedup vs baseline: 1.5487x; 1.0880x over previous
//
#include <hip/hip_runtime.h>

// Problem constants
#define BB 4
#define TT 2048
#define CC 768
#define HH 12
#define DD 64
#define MM (BB * TT)   // 8192 rows in the flattened [B*T, C] GEMMs

// 0.125 (1/sqrt(64)) * log2(e) folded into Q projection so softmax uses exp2 directly
#define QSCALE 0.18033688011112042f

typedef __attribute__((ext_vector_type(8))) __bf16 bf16x8;
typedef __attribute__((ext_vector_type(4))) __bf16 bf16x4;
typedef __attribute__((ext_vector_type(4))) float f32x4;

// ---------------------------------------------------------------------------
// global -> LDS async copy, 16B per lane. LDS dest is WAVE-UNIFORM base
// (HW adds lane*16); global source is per-lane (pre-swizzled so the
// XOR-swizzled ds_read side matches — both-sides-or-neither rule).
// ---------------------------------------------------------------------------
__device__ inline void gload16(const void* g, void* l) {
  __builtin_amdgcn_global_load_lds(
      (const __attribute__((address_space(1))) unsigned int*)g,
      (__attribute__((address_space(3))) unsigned int*)l, 16, 0, 0);
}

// ---------------------------------------------------------------------------
// fp32 -> bf16 cast kernels (vectorized: 2x float4 in, 1x 16B bf16x8 out)
// ---------------------------------------------------------------------------
__device__ inline void cast_body(const float* __restrict__ s, __bf16* __restrict__ d) {
  long i = ((long)blockIdx.x * 256 + threadIdx.x) * 8;
  f32x4 a = *(const f32x4*)(s + i);
  f32x4 b = *(const f32x4*)(s + i + 4);
  bf16x8 o;
  o[0] = (__bf16)a[0]; o[1] = (__bf16)a[1]; o[2] = (__bf16)a[2]; o[3] = (__bf16)a[3];
  o[4] = (__bf16)b[0]; o[5] = (__bf16)b[1]; o[6] = (__bf16)b[2]; o[7] = (__bf16)b[3];
  *(bf16x8*)(d + i) = o;
}

__global__ __launch_bounds__(256) void cast3(const float* __restrict__ s0, const float* __restrict__ s1,
                                             const float* __restrict__ s2,
                                             __bf16* d0, __bf16* d1, __bf16* d2) {
  const float* s = blockIdx.y == 0 ? s0 : blockIdx.y == 1 ? s1 : s2;
  __bf16* d = blockIdx.y == 0 ? d0 : blockIdx.y == 1 ? d1 : d2;
  cast_body(s, d);
}

__global__ __launch_bounds__(256) void cast4(const float* __restrict__ s0, const float* __restrict__ s1,
                                             const float* __restrict__ s2, const float* __restrict__ s3,
                                             __bf16* d0, __bf16* d1, __bf16* d2, __bf16* d3) {
  const float* s; __bf16* d;
  switch (blockIdx.y) {
    case 0: s = s0; d = d0; break;
    case 1: s = s1; d = d1; break;
    case 2: s = s2; d = d2; break;
    default: s = s3; d = d3; break;
  }
  cast_body(s, d);
}

// ---------------------------------------------------------------------------
// GEMM helpers
// ---------------------------------------------------------------------------
__device__ inline void stage_tile(const __bf16* __restrict__ A, const __bf16* __restrict__ W,
                                  long m0, long n0, int k0,
                                  __bf16* As, __bf16* Bs, int wave, int lane) {
#pragma unroll
  for (int i = 0; i < 4; ++i) {
    const int r = wave + i * 4;          // 16 regions of 1KB per matrix
    const int L = r * 1024 + lane * 16;  // this lane's linear LDS byte
    const int row = L >> 7;              // 128B per row (64 bf16)
    const int sc = (L >> 4) & 7;
    const int gc = sc ^ (row & 7);       // inverse-swizzled source chunk
    gload16(A + (m0 + row) * CC + k0 + gc * 8, As + r * 512);
    gload16(W + (n0 + row) * CC + k0 + gc * 8, Bs + r * 512);
  }
}

__device__ inline void compute_tile(const __bf16* As, const __bf16* Bs, f32x4 (&acc)[4][4],
                                    int wr, int wc, int l15, int g) {
#pragma unroll
  for (int kk = 0; kk < 2; ++kk) {
    bf16x8 af[4], bfr[4];
#pragma unroll
    for (int mi = 0; mi < 4; ++mi) {
      const int row = wr + mi * 16 + l15;
      const int c = (kk * 4 + g) ^ (row & 7);
      af[mi] = *(const bf16x8*)&As[row * 64 + c * 8];
    }
#pragma unroll
    for (int ni = 0; ni < 4; ++ni) {
      const int row = wc + ni * 16 + l15;
      const int c = (kk * 4 + g) ^ (row & 7);
      bfr[ni] = *(const bf16x8*)&Bs[row * 64 + c * 8];
    }
    __builtin_amdgcn_s_setprio(1);
#pragma unroll
    for (int mi = 0; mi < 4; ++mi)
#pragma unroll
      for (int ni = 0; ni < 4; ++ni)
        acc[mi][ni] = __builtin_amdgcn_mfma_f32_16x16x32_bf16(af[mi], bfr[ni], acc[mi][ni], 0, 0, 0);
    __builtin_amdgcn_s_setprio(0);
  }
}

// ---------------------------------------------------------------------------
// GEMM: C[m,n] = sum_k A[m,k] * W[n,k]   (x @ W^T, both bf16 row-major)
// Tile 128x128, BK=64, 256 threads (4 waves, 2x2 of 64x64), 16x16x32 MFMA.
// 2-phase double-buffered K-loop; one __syncthreads per iter.
// 1-D grid + XCD-aware remap: the 6 n-tiles of each (m,z) sit on ONE XCD
// (consecutive slots) so the A row-panel is fetched from HBM once and the
// W panel stays L2-hot. MODE0 grid = 1152 = 8*144; MODE1 grid = 384 = 8*48.
// Epilogue restages C through swizzled LDS for coalesced vector stores.
// MODE 0: bf16 head layouts: z==0 Q (pre-scaled) [bh][t][d], z==1 K [bh][t][d],
//         z==2 V TRANSPOSED [bh][d][t].
// MODE 1: fp32 row-major [M,768] (final output projection)
// ---------------------------------------------------------------------------
template <int MODE>
__global__ __launch_bounds__(256) void gemm_proj(
    const __bf16* __restrict__ A0, const __bf16* __restrict__ A1, const __bf16* __restrict__ A2,
    const __bf16* __restrict__ W0, const __bf16* __restrict__ W1, const __bf16* __restrict__ W2,
    void* D0, void* D1, void* D2) {
  __shared__ __align__(16) char smem[65536];
  __bf16* As0 = (__bf16*)smem;                    // 16 KB
  __bf16* Bs0 = (__bf16*)(smem + 16384);
  __bf16* As1 = (__bf16*)(smem + 32768);
  __bf16* Bs1 = (__bf16*)(smem + 49152);

  // XCD remap: id%8 = XCD (round-robin dispatch); consecutive slots on an XCD
  // enumerate n fastest, then (m,z).
  const int id = blockIdx.x;
  const int xcd = id & 7, slot = id >> 3;
  const int n_idx = slot % 6;
  const int mzg = xcd + 8 * (slot / 6);          // [0,192) MODE0 / [0,64) MODE1
  const int z = (MODE == 0) ? (mzg >> 6) : 0;
  const int m_idx = (MODE == 0) ? (mzg & 63) : mzg;

  const __bf16* __restrict__ A = z == 0 ? A0 : z == 1 ? A1 : A2;
  const __bf16* __restrict__ W = z == 0 ? W0 : z == 1 ? W1 : W2;
  const long m0 = (long)m_idx * 128;
  const long n0 = (long)n_idx * 128;
  const int tid = threadIdx.x;
  const int wave = tid >> 6, lane = tid & 63;
  const int l15 = lane & 15, g = lane >> 4;
  const int wr = (wave >> 1) * 64, wc = (wave & 1) * 64;

  f32x4 acc[4][4] = {};

  stage_tile(A, W, m0, n0, 0, As0, Bs0, wave, lane);
  __syncthreads();
  for (int kt = 0; kt < 12; kt += 2) {
    stage_tile(A, W, m0, n0, (kt + 1) * 64, As1, Bs1, wave, lane);
    compute_tile(As0, Bs0, acc, wr, wc, l15, g);
    __syncthreads();
    if (kt + 2 < 12) stage_tile(A, W, m0, n0, (kt + 2) * 64, As0, Bs0, wave, lane);
    compute_tile(As1, Bs1, acc, wr, wc, l15, g);
    __syncthreads();
  }

  // ---- epilogue via LDS restage, two passes of a 64x128 half-tile ----
  // C/D frag layout: col = lane&15, row = (lane>>4)*4 + j (m89-verified).
  const int b = (int)(m0 >> 11);
  const int t0 = (int)(m0 & (TT - 1));
  if (MODE == 1) {
    float* Ef = (float*)smem;                     // [64][128] f32, 32 KB
    float* Dst = (float*)D0;
    for (int p = 0; p < 2; ++p) {
      if (p) __syncthreads();
      if ((wr >> 6) == p) {
#pragma unroll
        for (int mi = 0; mi < 4; ++mi)
#pragma unroll
          for (int ni = 0; ni < 4; ++ni)
#pragma unroll
            for (int j = 0; j < 4; ++j) {
              const int ml = mi * 16 + g * 4 + j;           // 0..63
              const int n = wc + ni * 16 + l15;             // 0..127
              *(float*)((char*)Ef + ml * 512 + ((n * 4) ^ (((ml >> 2) & 7) << 4))) = acc[mi][ni][j];
            }
      }
      __syncthreads();
#pragma unroll
      for (int sw = 0; sw < 8; ++sw) {
        const int r = sw * 8 + (tid >> 5);
        const int c = (tid & 31) * 4;
        f32x4 vv = *(const f32x4*)((char*)Ef + r * 512 + ((c * 4) ^ (((r >> 2) & 7) << 4)));
        *(f32x4*)&Dst[(m0 + p * 64 + r) * CC + n0 + c] = vv;
      }
    }
  } else {
    __bf16* Eh = (__bf16*)smem;                   // [64][128] bf16, 16 KB
    __bf16* Dst = (__bf16*)(z == 0 ? D0 : z == 1 ? D1 : D2);
    for (int p = 0; p < 2; ++p) {
      if (p) __syncthreads();
      if (z != 2) {
        if ((wr >> 6) == p) {
#pragma unroll
          for (int mi = 0; mi < 4; ++mi)
#pragma unroll
            for (int ni = 0; ni < 4; ++ni)
#pragma unroll
              for (int j = 0; j < 4; ++j) {
                const int ml = mi * 16 + g * 4 + j;
                const int n = wc + ni * 16 + l15;
                float v = acc[mi][ni][j];
                if (z == 0) v *= QSCALE;
                *(__bf16*)((char*)Eh + ml * 256 + ((n * 2) ^ (((ml >> 2) & 7) << 4))) = (__bf16)v;
              }
        }
      } else {
        if ((wc >> 6) == p) {
#pragma unroll
          for (int mi = 0; mi < 4; ++mi)
#pragma unroll
            for (int ni = 0; ni < 4; ++ni)
#pragma unroll
              for (int j = 0; j < 4; ++j) {
                const int nl = ni * 16 + l15;                // 0..63 (d within half)
                const int mm = wr + mi * 16 + g * 4 + j;     // 0..127 (t)
                *(__bf16*)((char*)Eh + nl * 256 + ((mm * 2) ^ ((nl & 7) << 4))) = (__bf16)acc[mi][ni][j];
              }
        }
      }
      __syncthreads();
#pragma unroll
      for (int sw = 0; sw < 4; ++sw) {
        const int r = sw * 16 + (tid >> 4);
        const int c = (tid & 15) * 8;
        if (z != 2) {
          bf16x8 vv = *(const bf16x8*)((char*)Eh + r * 256 + ((c * 2) ^ (((r >> 2) & 7) << 4)));
          const int t = t0 + p * 64 + r;
          const int n = (int)n0 + c;
          const int h = n >> 6, d = n & 63;
          *(bf16x8*)&Dst[(((long)(b * HH + h)) * TT + t) * DD + d] = vv;
        } else {
          bf16x8 vv = *(const bf16x8*)((char*)Eh + r * 256 + ((c * 2) ^ ((r & 7) << 4)));
          const int n = (int)n0 + p * 64 + r;                // head-dim index
          const int h = n >> 6, d = n & 63;
          *(bf16x8*)&Dst[(((long)(b * HH + h)) * DD + d) * TT + t0 + c] = vv;
        }
      }
    }
  }
}

// ---------------------------------------------------------------------------
// Causal flash attention, bf16 MFMA, fp32 online softmax (base-2 domain).
// Block = 256 thr (4 waves). Balanced causal pairing: block a processes
// q-tiles {a, 31-a} -> every block does exactly 33 K-tile iterations.
// 1-D grid 768 = 8 XCD * 96 with XCD remap: all 16 q-blocks of a (b,h) sit on
// ONE XCD so K/V^T are fetched from HBM once per head and then hit that XCD's
// L2 (round-3 counters showed 187 MB fetch vs 38 MB ideal = cross-XCD dupes).
// K and V^T double-buffered via async global_load_lds; one __syncthreads per
// tile. Swapped QK^T (S^T = mfma(K, Q)) keeps each q-row's P in one lane.
// Steady-state softmax: per-lane partial lsum, hardware v_exp_f32
// (__builtin_amdgcn_exp2f), defer-max O-rescale, zero cross-lane ops.
// ---------------------------------------------------------------------------
__global__ __launch_bounds__(256) void attn_fwd(
    const __bf16* __restrict__ Qh, const __bf16* __restrict__ Kh,
    const __bf16* __restrict__ Vh, __bf16* __restrict__ Y) {
  __shared__ __bf16 Kl[2][64 * 64];     // [kv][d], chunk ^= kv&7
  __shared__ __bf16 Vl[2][64 * 64];     // V^T tile [d][kv], chunk ^= d&7
  __shared__ __bf16 Pl[4][16 * 64];     // per-wave P [q][64kv], chunk ^= q&7
  // total LDS = 16K + 16K + 8K = 40960 B -> 3 blocks/CU, 768 co-resident

  // XCD remap: 96 slots per XCD = 6 heads x 16 q-pair blocks
  const int id = blockIdx.x;
  const int xcd = id & 7, slot = id >> 3;
  const int a = slot & 15;              // q-tiles {a, 31-a}
  const int bh = xcd + 8 * (slot >> 4); // 0..47, all of a head on one XCD

  const int tid = threadIdx.x, wave = tid >> 6, lane = tid & 63;
  const int l15 = lane & 15, g = lane >> 4;
  const __bf16* Kbase = Kh + (long)bh * TT * DD;
  const __bf16* VTbase = Vh + (long)bh * DD * TT;   // [d][t]
  const int b = bh / HH, h = bh % HH;
  char* Pb = (char*)&Pl[wave][0];

  const int s_a = a + 1;                // tiles in phase 0
  const int total = 33;                 // (a+1) + (32-a)

  int qt = a;
  int qrow = qt * 64 + wave * 16 + l15;
  bf16x8 qf0, qf1;
  {
    const __bf16* qptr = Qh + ((long)bh * TT + qrow) * DD;
    qf0 = *(const bf16x8*)(qptr + g * 8);
    qf1 = *(const bf16x8*)(qptr + 32 + g * 8);
  }

  f32x4 oacc[4] = {};                   // O[q=g*4+j][d=ni*16+l15] per ni
  float m = -1e30f, lsum = 0.f;         // lsum is PER-LANE partial

  // prologue: stage tile 0 into buffer 0
#pragma unroll
  for (int i = 0; i < 2; ++i) {
    const int r = wave + i * 4;
    const int L = r * 1024 + lane * 16;
    const int row = L >> 7, sc = (L >> 4) & 7, gc = sc ^ (row & 7);
    gload16(Kbase + (long)row * DD + gc * 8, &Kl[0][r * 512]);
    gload16(VTbase + (long)row * TT + gc * 8, &Vl[0][r * 512]);
  }

  for (int s = 0; s < total; ++s) {
    __syncthreads();   // staged tile s visible; all waves done with tile s-1

    // --- issue async stage of tile s+1 into the other buffer ---
    if (s + 1 < total) {
      const int kt1 = (s + 1 >= s_a) ? (s + 1 - s_a) : (s + 1);
      const int kv1 = kt1 * 64;
      __bf16* Kd = Kl[(s + 1) & 1];
      __bf16* Vd = Vl[(s + 1) & 1];
#pragma unroll
      for (int i = 0; i < 2; ++i) {
        const int r = wave + i * 4;
        const int L = r * 1024 + lane * 16;
        const int row = L >> 7, sc = (L >> 4) & 7, gc = sc ^ (row & 7);
        gload16(Kbase + (long)(kv1 + row) * DD + gc * 8, Kd + r * 512);
        gload16(VTbase + (long)row * TT + kv1 + gc * 8, Vd + r * 512);
      }
    }

    // --- phase switch: write out q-tile a, start q-tile 31-a ---
    if (s == s_a) {
      float lrow = lsum + __shfl_xor(lsum, 16);
      lrow += __shfl_xor(lrow, 32);
#pragma unroll
      for (int j = 0; j < 4; ++j) {
        const float inv = 1.0f / __shfl(lrow, g * 4 + j);
        const int q = qt * 64 + wave * 16 + g * 4 + j;
#pragma unroll
        for (int ni = 0; ni < 4; ++ni)
          Y[((long)(b * TT + q)) * CC + h * DD + ni * 16 + l15] = (__bf16)(oacc[ni][j] * inv);
      }
      qt = 31 - a;
      qrow = qt * 64 + wave * 16 + l15;
      const __bf16* qptr = Qh + ((long)bh * TT + qrow) * DD;
      qf0 = *(const bf16x8*)(qptr + g * 8);
      qf1 = *(const bf16x8*)(qptr + 32 + g * 8);
#pragma unroll
      for (int ni = 0; ni < 4; ++ni) oacc[ni] = (f32x4){0.f, 0.f, 0.f, 0.f};
      m = -1e30f; lsum = 0.f;
    }

    const int kt = (s >= s_a) ? (s - s_a) : s;
    const int kv0 = kt * 64;
    const bool maskt = (kt == qt);       // only the diagonal tile masks
    const __bf16* Kc = Kl[s & 1];
    const __bf16* Vc = Vl[s & 1];

    // --- S^T = K * Q^T : sacc[mi][j] = S[qrow][kv0+mi*16+g*4+j] (log2-scaled)
    f32x4 sacc[4] = {};
    __builtin_amdgcn_s_setprio(1);
#pragma unroll
    for (int mi = 0; mi < 4; ++mi) {
      const int row = mi * 16 + l15;                 // kv_local
      const int c0 = g ^ (row & 7);
      const int c1 = (4 + g) ^ (row & 7);
      bf16x8 kfa = *(const bf16x8*)&Kc[row * 64 + c0 * 8];
      bf16x8 kfb = *(const bf16x8*)&Kc[row * 64 + c1 * 8];
      sacc[mi] = __builtin_amdgcn_mfma_f32_16x16x32_bf16(kfa, qf0, sacc[mi], 0, 0, 0);
      sacc[mi] = __builtin_amdgcn_mfma_f32_16x16x32_bf16(kfb, qf1, sacc[mi], 0, 0, 0);
    }
    __builtin_amdgcn_s_setprio(0);

    // --- online softmax, steady-state shuffle-free ---
    float ps[4][4];
    float tmax = -3e30f;
    if (maskt) {
#pragma unroll
      for (int mi = 0; mi < 4; ++mi)
#pragma unroll
        for (int j = 0; j < 4; ++j) {
          float sv = sacc[mi][j];
          const int kv = kv0 + mi * 16 + g * 4 + j;
          if (kv > qrow) sv = -3e30f;
          ps[mi][j] = sv;
          tmax = fmaxf(tmax, sv);
        }
    } else {
#pragma unroll
      for (int mi = 0; mi < 4; ++mi)
#pragma unroll
        for (int j = 0; j < 4; ++j) {
          const float sv = sacc[mi][j];
          ps[mi][j] = sv;
          tmax = fmaxf(tmax, sv);
        }
    }

    // defer-max: only rescale when some row's max grew by > 8 (P <= 2^8)
    if (!__all(tmax <= m + 8.0f)) {
      float full = fmaxf(tmax, __shfl_xor(tmax, 16));
      full = fmaxf(full, __shfl_xor(full, 32));
      const float mnew = fmaxf(m, full);
      const float corr = __builtin_amdgcn_exp2f(m - mnew);   // this lane's row corr
#pragma unroll
      for (int j = 0; j < 4; ++j) {
        const float cj = __shfl(corr, g * 4 + j);
#pragma unroll
        for (int ni = 0; ni < 4; ++ni) oacc[ni][j] *= cj;
      }
      lsum *= corr;
      m = mnew;
    }

#pragma unroll
    for (int mi = 0; mi < 4; ++mi) {
      bf16x4 pv;
#pragma unroll
      for (int j = 0; j < 4; ++j) {
        const float p = __builtin_amdgcn_exp2f(ps[mi][j] - m);  // 1x v_exp_f32
        lsum += p;
        pv[j] = (__bf16)p;
      }
      // P [q=l15][kv], stride 64, chunk ^= l15&7
      *(bf16x4*)(Pb + l15 * 128 + ((mi * 32 + g * 8) ^ ((l15 & 7) << 4))) = pv;
    }

    // --- PV: O += P * V  (B-fragments straight from V^T tile) ---
    __builtin_amdgcn_s_setprio(1);
#pragma unroll
    for (int ks = 0; ks < 2; ++ks) {
      bf16x8 pa = *(const bf16x8*)(Pb + l15 * 128 + ((ks * 64 + g * 16) ^ ((l15 & 7) << 4)));
#pragma unroll
      for (int ni = 0; ni < 4; ++ni) {
        const int d = ni * 16 + l15;
        const int c = (ks * 4 + g) ^ (d & 7);
        bf16x8 vf = *(const bf16x8*)&Vc[d * 64 + c * 8];
        oacc[ni] = __builtin_amdgcn_mfma_f32_16x16x32_bf16(pa, vf, oacc[ni], 0, 0, 0);
      }
    }
    __builtin_amdgcn_s_setprio(0);
  }

  // --- epilogue: write out q-tile 31-a ---
  {
    float lrow = lsum + __shfl_xor(lsum, 16);
    lrow += __shfl_xor(lrow, 32);
#pragma unroll
    for (int j = 0; j < 4; ++j) {
      const float inv = 1.0f / __shfl(lrow, g * 4 + j);
      const int q = qt * 64 + wave * 16 + g * 4 + j;
#pragma unroll
      for (int ni = 0; ni < 4; ++ni)
        Y[((long)(b * TT + q)) * CC + h * DD + ni * 16 + l15] = (__bf16)(oacc[ni][j] * inv);
    }
  }
}

// ---------------------------------------------------------------------------
// Host launcher
// ---------------------------------------------------------------------------
extern "C" void kernel_launch(void* const* d_in, const int* in_sizes, int n_in,
                              void* d_out, int out_size, void* d_ws, size_t ws_size,
                              hipStream_t stream) {
  (void)in_sizes; (void)n_in; (void)out_size; (void)ws_size;
  const float* q  = (const float*)d_in[0];
  const float* k  = (const float*)d_in[1];
  const float* v  = (const float*)d_in[2];
  const float* wq = (const float*)d_in[3];
  const float* wk = (const float*)d_in[4];
  const float* wv = (const float*)d_in[5];
  const float* wo = (const float*)d_in[6];

  char* ws = (char*)d_ws;
  const long SZX = (long)MM * CC * 2;      // 12,582,912 B per [8192,768] bf16
  const long SZW = (long)CC * CC * 2;      // 1,179,648 B per weight bf16
  __bf16* xq  = (__bf16*)(ws);
  __bf16* xk  = (__bf16*)(ws + SZX);
  __bf16* xv  = (__bf16*)(ws + 2 * SZX);
  __bf16* wwq = (__bf16*)(ws + 3 * SZX);
  __bf16* wwk = (__bf16*)(ws + 3 * SZX + SZW);
  __bf16* wwv = (__bf16*)(ws + 3 * SZX + 2 * SZW);
  __bf16* wwo = (__bf16*)(ws + 3 * SZX + 3 * SZW);
  __bf16* qh  = (__bf16*)(ws + 3 * SZX + 4 * SZW);
  __bf16* kh  = (__bf16*)(ws + 4 * SZX + 4 * SZW);
  __bf16* vh  = (__bf16*)(ws + 5 * SZX + 4 * SZW);  // V^T head-major [bh][d][t]
  __bf16* y   = xq;   // alias: xq is dead once projections are done

  // 1) casts
  cast3<<<dim3((MM * CC) / 2048, 3, 1), 256, 0, stream>>>(q, k, v, xq, xk, xv);
  cast4<<<dim3((CC * CC) / 2048, 4, 1), 256, 0, stream>>>(wq, wk, wv, wo, wwq, wwk, wwv, wwo);
  // 2) fused QKV projections -> head layout bf16 (Q pre-scaled, V transposed)
  gemm_proj<0><<<dim3(1152, 1, 1), 256, 0, stream>>>(xq, xk, xv, wwq, wwk, wwv, qh, kh, vh);
  // 3) causal flash attention (balanced pairing + XCD grouping) -> y bf16
  attn_fwd<<<dim3(768, 1, 1), 256, 0, stream>>>(qh, kh, vh, y);
  // 4) output projection -> fp32 d_out
  gemm_proj<1><<<dim3(384, 1, 1), 256, 0, stream>>>(y, y, y, wwo, wwo, wwo, d_out, d_out, d_out);
}

// Round 7
// 233.502 us; speedup vs baseline: 1.5966x; 1.0309x over previous
//
#include <hip/hip_runtime.h>

// Problem constants
#define BB 4
#define TT 2048
#define CC 768
#define HH 12
#define DD 64
#define MM (BB * TT)   // 8192 rows in the flattened [B*T, C] GEMMs

// 0.125 (1/sqrt(64)) * log2(e) folded into Q projection so softmax uses exp2 directly
#define QSCALE 0.18033688011112042f

typedef __attribute__((ext_vector_type(8))) __bf16 bf16x8;
typedef __attribute__((ext_vector_type(4))) __bf16 bf16x4;
typedef __attribute__((ext_vector_type(4))) float f32x4;

// ---------------------------------------------------------------------------
// global -> LDS async copy, 16B per lane. LDS dest is WAVE-UNIFORM base
// (HW adds lane*16); global source is per-lane (pre-swizzled so the
// XOR-swizzled ds_read side matches — both-sides-or-neither rule).
// ---------------------------------------------------------------------------
__device__ inline void gload16(const void* g, void* l) {
  __builtin_amdgcn_global_load_lds(
      (const __attribute__((address_space(1))) unsigned int*)g,
      (__attribute__((address_space(3))) unsigned int*)l, 16, 0, 0);
}

// ---------------------------------------------------------------------------
// Single merged fp32 -> bf16 cast kernel (one dispatch, flat grid, no idle
// blocks). Big tensors q/k/v: 3x3072 blocks; weights: 4x288 blocks.
// ---------------------------------------------------------------------------
__global__ __launch_bounds__(256) void cast_all(
    const float* __restrict__ q, const float* __restrict__ k, const float* __restrict__ v,
    const float* __restrict__ wq, const float* __restrict__ wk,
    const float* __restrict__ wv, const float* __restrict__ wo,
    __bf16* xq, __bf16* xk, __bf16* xv,
    __bf16* wwq, __bf16* wwk, __bf16* wwv, __bf16* wwo) {
  const int id = blockIdx.x;
  const float* s; __bf16* d; long base;
  if (id < 9216) {                        // 3 x 3072 blocks of 2048 elems
    const int t = id / 3072;
    base = (long)(id % 3072) * 2048;
    s = t == 0 ? q : t == 1 ? k : v;
    d = t == 0 ? xq : t == 1 ? xk : xv;
  } else {                                // 4 x 288 blocks of 2048 elems
    const int r = id - 9216;
    const int t = r / 288;
    base = (long)(r % 288) * 2048;
    s = t == 0 ? wq : t == 1 ? wk : t == 2 ? wv : wo;
    d = t == 0 ? wwq : t == 1 ? wwk : t == 2 ? wwv : wwo;
  }
  const long i = base + (long)threadIdx.x * 8;
  f32x4 a = *(const f32x4*)(s + i);
  f32x4 b = *(const f32x4*)(s + i + 4);
  bf16x8 o;
  o[0] = (__bf16)a[0]; o[1] = (__bf16)a[1]; o[2] = (__bf16)a[2]; o[3] = (__bf16)a[3];
  o[4] = (__bf16)b[0]; o[5] = (__bf16)b[1]; o[6] = (__bf16)b[2]; o[7] = (__bf16)b[3];
  *(bf16x8*)(d + i) = o;
}

// ---------------------------------------------------------------------------
// GEMM helpers
// ---------------------------------------------------------------------------
__device__ inline void stage_tile(const __bf16* __restrict__ A, const __bf16* __restrict__ W,
                                  long m0, long n0, int k0,
                                  __bf16* As, __bf16* Bs, int wave, int lane) {
#pragma unroll
  for (int i = 0; i < 4; ++i) {
    const int r = wave + i * 4;          // 16 regions of 1KB per matrix
    const int L = r * 1024 + lane * 16;  // this lane's linear LDS byte
    const int row = L >> 7;              // 128B per row (64 bf16)
    const int sc = (L >> 4) & 7;
    const int gc = sc ^ (row & 7);       // inverse-swizzled source chunk
    gload16(A + (m0 + row) * CC + k0 + gc * 8, As + r * 512);
    gload16(W + (n0 + row) * CC + k0 + gc * 8, Bs + r * 512);
  }
}

__device__ inline void compute_tile(const __bf16* As, const __bf16* Bs, f32x4 (&acc)[4][4],
                                    int wr, int wc, int l15, int g) {
#pragma unroll
  for (int kk = 0; kk < 2; ++kk) {
    bf16x8 af[4], bfr[4];
#pragma unroll
    for (int mi = 0; mi < 4; ++mi) {
      const int row = wr + mi * 16 + l15;
      const int c = (kk * 4 + g) ^ (row & 7);
      af[mi] = *(const bf16x8*)&As[row * 64 + c * 8];
    }
#pragma unroll
    for (int ni = 0; ni < 4; ++ni) {
      const int row = wc + ni * 16 + l15;
      const int c = (kk * 4 + g) ^ (row & 7);
      bfr[ni] = *(const bf16x8*)&Bs[row * 64 + c * 8];
    }
    __builtin_amdgcn_s_setprio(1);
#pragma unroll
    for (int mi = 0; mi < 4; ++mi)
#pragma unroll
      for (int ni = 0; ni < 4; ++ni)
        acc[mi][ni] = __builtin_amdgcn_mfma_f32_16x16x32_bf16(af[mi], bfr[ni], acc[mi][ni], 0, 0, 0);
    __builtin_amdgcn_s_setprio(0);
  }
}

// ---------------------------------------------------------------------------
// GEMM: C[m,n] = sum_k A[m,k] * W[n,k]   (x @ W^T, both bf16 row-major)
// Tile 128x128, BK=64, 256 threads (4 waves, 2x2 of 64x64), 16x16x32 MFMA.
// SINGLE-buffered 32 KB LDS (m97 structure): sync; stage; sync; compute.
// Round-3's 64 KB double-buffer halved occupancy (2 blocks/CU — the m132
// regression); 32 KB + launch_bounds(256,4) gives 4 blocks/CU and the
// cross-block overlap covers the barrier drain.
// 1-D grid + XCD remap: the 6 n-tiles of each (m,z) on ONE XCD.
// Epilogue restages C through swizzled LDS for coalesced vector stores.
// MODE 0: bf16 head layouts: z==0 Q (pre-scaled) [bh][t][d], z==1 K [bh][t][d],
//         z==2 V TRANSPOSED [bh][d][t].
// MODE 1: fp32 row-major [M,768] (final output projection)
// ---------------------------------------------------------------------------
template <int MODE>
__global__ __launch_bounds__(256, 4) void gemm_proj(
    const __bf16* __restrict__ A0, const __bf16* __restrict__ A1, const __bf16* __restrict__ A2,
    const __bf16* __restrict__ W0, const __bf16* __restrict__ W1, const __bf16* __restrict__ W2,
    void* D0, void* D1, void* D2) {
  __shared__ __align__(16) char smem[32768];
  __bf16* As = (__bf16*)smem;                     // 16 KB
  __bf16* Bs = (__bf16*)(smem + 16384);           // 16 KB

  // XCD remap: id%8 = XCD (round-robin dispatch); consecutive slots on an XCD
  // enumerate n fastest, then (m,z).
  const int id = blockIdx.x;
  const int xcd = id & 7, slot = id >> 3;
  const int n_idx = slot % 6;
  const int mzg = xcd + 8 * (slot / 6);          // [0,192) MODE0 / [0,64) MODE1
  const int z = (MODE == 0) ? (mzg >> 6) : 0;
  const int m_idx = (MODE == 0) ? (mzg & 63) : mzg;

  const __bf16* __restrict__ A = z == 0 ? A0 : z == 1 ? A1 : A2;
  const __bf16* __restrict__ W = z == 0 ? W0 : z == 1 ? W1 : W2;
  const long m0 = (long)m_idx * 128;
  const long n0 = (long)n_idx * 128;
  const int tid = threadIdx.x;
  const int wave = tid >> 6, lane = tid & 63;
  const int l15 = lane & 15, g = lane >> 4;
  const int wr = (wave >> 1) * 64, wc = (wave & 1) * 64;

  f32x4 acc[4][4] = {};

  for (int kt = 0; kt < 12; ++kt) {
    __syncthreads();                       // all waves done reading tile kt-1
    stage_tile(A, W, m0, n0, kt * 64, As, Bs, wave, lane);
    __syncthreads();                       // vmcnt(0) drain: staged data visible
    compute_tile(As, Bs, acc, wr, wc, l15, g);
  }
  __syncthreads();                         // LDS reuse by epilogue

  // ---- epilogue via LDS restage, two passes of a 64x128 half-tile ----
  // C/D frag layout: col = lane&15, row = (lane>>4)*4 + j (m89-verified).
  const int b = (int)(m0 >> 11);
  const int t0 = (int)(m0 & (TT - 1));
  if (MODE == 1) {
    float* Ef = (float*)smem;                     // [64][128] f32, 32 KB
    float* Dst = (float*)D0;
    for (int p = 0; p < 2; ++p) {
      if (p) __syncthreads();
      if ((wr >> 6) == p) {
#pragma unroll
        for (int mi = 0; mi < 4; ++mi)
#pragma unroll
          for (int ni = 0; ni < 4; ++ni)
#pragma unroll
            for (int j = 0; j < 4; ++j) {
              const int ml = mi * 16 + g * 4 + j;           // 0..63
              const int n = wc + ni * 16 + l15;             // 0..127
              *(float*)((char*)Ef + ml * 512 + ((n * 4) ^ (((ml >> 2) & 7) << 4))) = acc[mi][ni][j];
            }
      }
      __syncthreads();
#pragma unroll
      for (int sw = 0; sw < 8; ++sw) {
        const int r = sw * 8 + (tid >> 5);
        const int c = (tid & 31) * 4;
        f32x4 vv = *(const f32x4*)((char*)Ef + r * 512 + ((c * 4) ^ (((r >> 2) & 7) << 4)));
        *(f32x4*)&Dst[(m0 + p * 64 + r) * CC + n0 + c] = vv;
      }
    }
  } else {
    __bf16* Eh = (__bf16*)smem;                   // [64][128] bf16, 16 KB
    __bf16* Dst = (__bf16*)(z == 0 ? D0 : z == 1 ? D1 : D2);
    for (int p = 0; p < 2; ++p) {
      if (p) __syncthreads();
      if (z != 2) {
        if ((wr >> 6) == p) {
#pragma unroll
          for (int mi = 0; mi < 4; ++mi)
#pragma unroll
            for (int ni = 0; ni < 4; ++ni)
#pragma unroll
              for (int j = 0; j < 4; ++j) {
                const int ml = mi * 16 + g * 4 + j;
                const int n = wc + ni * 16 + l15;
                float v = acc[mi][ni][j];
                if (z == 0) v *= QSCALE;
                *(__bf16*)((char*)Eh + ml * 256 + ((n * 2) ^ (((ml >> 2) & 7) << 4))) = (__bf16)v;
              }
        }
      } else {
        if ((wc >> 6) == p) {
#pragma unroll
          for (int mi = 0; mi < 4; ++mi)
#pragma unroll
            for (int ni = 0; ni < 4; ++ni)
#pragma unroll
              for (int j = 0; j < 4; ++j) {
                const int nl = ni * 16 + l15;                // 0..63 (d within half)
                const int mm = wr + mi * 16 + g * 4 + j;     // 0..127 (t)
                *(__bf16*)((char*)Eh + nl * 256 + ((mm * 2) ^ ((nl & 7) << 4))) = (__bf16)acc[mi][ni][j];
              }
        }
      }
      __syncthreads();
#pragma unroll
      for (int sw = 0; sw < 4; ++sw) {
        const int r = sw * 16 + (tid >> 4);
        const int c = (tid & 15) * 8;
        if (z != 2) {
          bf16x8 vv = *(const bf16x8*)((char*)Eh + r * 256 + ((c * 2) ^ (((r >> 2) & 7) << 4)));
          const int t = t0 + p * 64 + r;
          const int n = (int)n0 + c;
          const int h = n >> 6, d = n & 63;
          *(bf16x8*)&Dst[(((long)(b * HH + h)) * TT + t) * DD + d] = vv;
        } else {
          bf16x8 vv = *(const bf16x8*)((char*)Eh + r * 256 + ((c * 2) ^ ((r & 7) << 4)));
          const int n = (int)n0 + p * 64 + r;                // head-dim index
          const int h = n >> 6, d = n & 63;
          *(bf16x8*)&Dst[(((long)(b * HH + h)) * DD + d) * TT + t0 + c] = vv;
        }
      }
    }
  }
}

// ---------------------------------------------------------------------------
// Causal flash attention, bf16 MFMA, fp32 online softmax (base-2 domain).
// Block = 256 thr (4 waves). Balanced causal pairing: block a processes
// q-tiles {a, 31-a} -> every block does exactly 33 K-tile iterations.
// 1-D grid 768 = 8 XCD * 96 with XCD remap (all 16 q-blocks of a head on one
// XCD: round-5 counters confirmed FETCH 187 -> 18.5 MB).
// K and V^T double-buffered via async global_load_lds; one __syncthreads per
// tile. Swapped QK^T (S^T = mfma(K, Q)) keeps each q-row's P in one lane.
// Softmax VALU diet (round-5: VALUBusy 59% is the binding pipe):
//  - row-sum lsum computed on the MATRIX pipe: lacc = mfma(P, ones) — the
//    all-ones B makes every D column the row sum, lane-local in lacc[j];
//    removes 16 VALU adds/tile and ALL epilogue lsum shuffles.
//  - fmax tree (max3-fusable) instead of a 16-deep sequential chain.
//  - defer-max O-rescale; hardware v_exp_f32.
// ---------------------------------------------------------------------------
__global__ __launch_bounds__(256) void attn_fwd(
    const __bf16* __restrict__ Qh, const __bf16* __restrict__ Kh,
    const __bf16* __restrict__ Vh, __bf16* __restrict__ Y) {
  __shared__ __bf16 Kl[2][64 * 64];     // [kv][d], chunk ^= kv&7
  __shared__ __bf16 Vl[2][64 * 64];     // V^T tile [d][kv], chunk ^= d&7
  __shared__ __bf16 Pl[4][16 * 64];     // per-wave P [q][64kv], chunk ^= q&7
  // total LDS = 16K + 16K + 8K = 40960 B -> 4 blocks/CU ceiling; 768 = 3/CU

  // XCD remap: 96 slots per XCD = 6 heads x 16 q-pair blocks
  const int id = blockIdx.x;
  const int xcd = id & 7, slot = id >> 3;
  const int a = slot & 15;              // q-tiles {a, 31-a}
  const int bh = xcd + 8 * (slot >> 4); // 0..47, all of a head on one XCD

  const int tid = threadIdx.x, wave = tid >> 6, lane = tid & 63;
  const int l15 = lane & 15, g = lane >> 4;
  const __bf16* Kbase = Kh + (long)bh * TT * DD;
  const __bf16* VTbase = Vh + (long)bh * DD * TT;   // [d][t]
  const int b = bh / HH, h = bh % HH;
  char* Pb = (char*)&Pl[wave][0];

  const int s_a = a + 1;                // tiles in phase 0
  const int total = 33;                 // (a+1) + (32-a)

  bf16x8 ones;
#pragma unroll
  for (int i = 0; i < 8; ++i) ones[i] = (__bf16)1.0f;

  int qt = a;
  int qrow = qt * 64 + wave * 16 + l15;
  bf16x8 qf0, qf1;
  {
    const __bf16* qptr = Qh + ((long)bh * TT + qrow) * DD;
    qf0 = *(const bf16x8*)(qptr + g * 8);
    qf1 = *(const bf16x8*)(qptr + 32 + g * 8);
  }

  f32x4 oacc[4] = {};                   // O[q=g*4+j][d=ni*16+l15] per ni
  f32x4 lacc = {};                      // row-sum acc: lacc[j] = lsum[q=g*4+j]
  float m = -1e30f;

  // prologue: stage tile 0 into buffer 0
#pragma unroll
  for (int i = 0; i < 2; ++i) {
    const int r = wave + i * 4;
    const int L = r * 1024 + lane * 16;
    const int row = L >> 7, sc = (L >> 4) & 7, gc = sc ^ (row & 7);
    gload16(Kbase + (long)row * DD + gc * 8, &Kl[0][r * 512]);
    gload16(VTbase + (long)row * TT + gc * 8, &Vl[0][r * 512]);
  }

  for (int s = 0; s < total; ++s) {
    __syncthreads();   // staged tile s visible; all waves done with tile s-1

    // --- issue async stage of tile s+1 into the other buffer ---
    if (s + 1 < total) {
      const int kt1 = (s + 1 >= s_a) ? (s + 1 - s_a) : (s + 1);
      const int kv1 = kt1 * 64;
      __bf16* Kd = Kl[(s + 1) & 1];
      __bf16* Vd = Vl[(s + 1) & 1];
#pragma unroll
      for (int i = 0; i < 2; ++i) {
        const int r = wave + i * 4;
        const int L = r * 1024 + lane * 16;
        const int row = L >> 7, sc = (L >> 4) & 7, gc = sc ^ (row & 7);
        gload16(Kbase + (long)(kv1 + row) * DD + gc * 8, Kd + r * 512);
        gload16(VTbase + (long)row * TT + kv1 + gc * 8, Vd + r * 512);
      }
    }

    // --- phase switch: write out q-tile a, start q-tile 31-a ---
    if (s == s_a) {
#pragma unroll
      for (int j = 0; j < 4; ++j) {
        const float inv = 1.0f / lacc[j];     // lane-local row sum (ones-MFMA)
        const int q = qt * 64 + wave * 16 + g * 4 + j;
#pragma unroll
        for (int ni = 0; ni < 4; ++ni)
          Y[((long)(b * TT + q)) * CC + h * DD + ni * 16 + l15] = (__bf16)(oacc[ni][j] * inv);
      }
      qt = 31 - a;
      qrow = qt * 64 + wave * 16 + l15;
      const __bf16* qptr = Qh + ((long)bh * TT + qrow) * DD;
      qf0 = *(const bf16x8*)(qptr + g * 8);
      qf1 = *(const bf16x8*)(qptr + 32 + g * 8);
#pragma unroll
      for (int ni = 0; ni < 4; ++ni) oacc[ni] = (f32x4){0.f, 0.f, 0.f, 0.f};
      lacc = (f32x4){0.f, 0.f, 0.f, 0.f};
      m = -1e30f;
    }

    const int kt = (s >= s_a) ? (s - s_a) : s;
    const int kv0 = kt * 64;
    const bool maskt = (kt == qt);       // only the diagonal tile masks
    const __bf16* Kc = Kl[s & 1];
    const __bf16* Vc = Vl[s & 1];

    // --- S^T = K * Q^T : sacc[mi][j] = S[qrow][kv0+mi*16+g*4+j] (log2-scaled)
    f32x4 sacc[4] = {};
    __builtin_amdgcn_s_setprio(1);
#pragma unroll
    for (int mi = 0; mi < 4; ++mi) {
      const int row = mi * 16 + l15;                 // kv_local
      const int c0 = g ^ (row & 7);
      const int c1 = (4 + g) ^ (row & 7);
      bf16x8 kfa = *(const bf16x8*)&Kc[row * 64 + c0 * 8];
      bf16x8 kfb = *(const bf16x8*)&Kc[row * 64 + c1 * 8];
      sacc[mi] = __builtin_amdgcn_mfma_f32_16x16x32_bf16(kfa, qf0, sacc[mi], 0, 0, 0);
      sacc[mi] = __builtin_amdgcn_mfma_f32_16x16x32_bf16(kfb, qf1, sacc[mi], 0, 0, 0);
    }
    __builtin_amdgcn_s_setprio(0);

    // --- online softmax, steady-state shuffle-free ---
    float ps[4][4];
    float tmx[4];
    if (maskt) {
#pragma unroll
      for (int mi = 0; mi < 4; ++mi) {
#pragma unroll
        for (int j = 0; j < 4; ++j) {
          float sv = sacc[mi][j];
          const int kv = kv0 + mi * 16 + g * 4 + j;
          if (kv > qrow) sv = -3e30f;
          ps[mi][j] = sv;
        }
        tmx[mi] = fmaxf(fmaxf(ps[mi][0], ps[mi][1]), fmaxf(ps[mi][2], ps[mi][3]));
      }
    } else {
#pragma unroll
      for (int mi = 0; mi < 4; ++mi) {
#pragma unroll
        for (int j = 0; j < 4; ++j) ps[mi][j] = sacc[mi][j];
        tmx[mi] = fmaxf(fmaxf(ps[mi][0], ps[mi][1]), fmaxf(ps[mi][2], ps[mi][3]));
      }
    }
    const float tmax = fmaxf(fmaxf(tmx[0], tmx[1]), fmaxf(tmx[2], tmx[3]));

    // defer-max: only rescale when some row's max grew by > 8 (P <= 2^8)
    if (!__all(tmax <= m + 8.0f)) {
      float full = fmaxf(tmax, __shfl_xor(tmax, 16));
      full = fmaxf(full, __shfl_xor(full, 32));
      const float mnew = fmaxf(m, full);
      const float corr = __builtin_amdgcn_exp2f(m - mnew);   // this lane's row corr
#pragma unroll
      for (int j = 0; j < 4; ++j) {
        const float cj = __shfl(corr, g * 4 + j);
        lacc[j] *= cj;
#pragma unroll
        for (int ni = 0; ni < 4; ++ni) oacc[ni][j] *= cj;
      }
      m = mnew;
    }

#pragma unroll
    for (int mi = 0; mi < 4; ++mi) {
      bf16x4 pv;
#pragma unroll
      for (int j = 0; j < 4; ++j)
        pv[j] = (__bf16)__builtin_amdgcn_exp2f(ps[mi][j] - m);  // 1x v_exp_f32
      // P [q=l15][kv], stride 64, chunk ^= l15&7
      *(bf16x4*)(Pb + l15 * 128 + ((mi * 32 + g * 8) ^ ((l15 & 7) << 4))) = pv;
    }

    // --- PV: O += P * V ; row-sum via ones-MFMA (matrix pipe, not VALU) ---
    __builtin_amdgcn_s_setprio(1);
#pragma unroll
    for (int ks = 0; ks < 2; ++ks) {
      bf16x8 pa = *(const bf16x8*)(Pb + l15 * 128 + ((ks * 64 + g * 16) ^ ((l15 & 7) << 4)));
      lacc = __builtin_amdgcn_mfma_f32_16x16x32_bf16(pa, ones, lacc, 0, 0, 0);
#pragma unroll
      for (int ni = 0; ni < 4; ++ni) {
        const int d = ni * 16 + l15;
        const int c = (ks * 4 + g) ^ (d & 7);
        bf16x8 vf = *(const bf16x8*)&Vc[d * 64 + c * 8];
        oacc[ni] = __builtin_amdgcn_mfma_f32_16x16x32_bf16(pa, vf, oacc[ni], 0, 0, 0);
      }
    }
    __builtin_amdgcn_s_setprio(0);
  }

  // --- epilogue: write out q-tile 31-a ---
#pragma unroll
  for (int j = 0; j < 4; ++j) {
    const float inv = 1.0f / lacc[j];
    const int q = qt * 64 + wave * 16 + g * 4 + j;
#pragma unroll
    for (int ni = 0; ni < 4; ++ni)
      Y[((long)(b * TT + q)) * CC + h * DD + ni * 16 + l15] = (__bf16)(oacc[ni][j] * inv);
  }
}

// ---------------------------------------------------------------------------
// Host launcher
// ---------------------------------------------------------------------------
extern "C" void kernel_launch(void* const* d_in, const int* in_sizes, int n_in,
                              void* d_out, int out_size, void* d_ws, size_t ws_size,
                              hipStream_t stream) {
  (void)in_sizes; (void)n_in; (void)out_size; (void)ws_size;
  const float* q  = (const float*)d_in[0];
  const float* k  = (const float*)d_in[1];
  const float* v  = (const float*)d_in[2];
  const float* wq = (const float*)d_in[3];
  const float* wk = (const float*)d_in[4];
  const float* wv = (const float*)d_in[5];
  const float* wo = (const float*)d_in[6];

  char* ws = (char*)d_ws;
  const long SZX = (long)MM * CC * 2;      // 12,582,912 B per [8192,768] bf16
  const long SZW = (long)CC * CC * 2;      // 1,179,648 B per weight bf16
  __bf16* xq  = (__bf16*)(ws);
  __bf16* xk  = (__bf16*)(ws + SZX);
  __bf16* xv  = (__bf16*)(ws + 2 * SZX);
  __bf16* wwq = (__bf16*)(ws + 3 * SZX);
  __bf16* wwk = (__bf16*)(ws + 3 * SZX + SZW);
  __bf16* wwv = (__bf16*)(ws + 3 * SZX + 2 * SZW);
  __bf16* wwo = (__bf16*)(ws + 3 * SZX + 3 * SZW);
  __bf16* qh  = (__bf16*)(ws + 3 * SZX + 4 * SZW);
  __bf16* kh  = (__bf16*)(ws + 4 * SZX + 4 * SZW);
  __bf16* vh  = (__bf16*)(ws + 5 * SZX + 4 * SZW);  // V^T head-major [bh][d][t]
  __bf16* y   = xq;   // alias: xq is dead once projections are done

  // 1) single merged cast dispatch (9216 big + 1152 weight blocks)
  cast_all<<<dim3(10368, 1, 1), 256, 0, stream>>>(q, k, v, wq, wk, wv, wo,
                                                  xq, xk, xv, wwq, wwk, wwv, wwo);
  // 2) fused QKV projections -> head layout bf16 (Q pre-scaled, V transposed)
  gemm_proj<0><<<dim3(1152, 1, 1), 256, 0, stream>>>(xq, xk, xv, wwq, wwk, wwv, qh, kh, vh);
  // 3) causal flash attention (balanced pairing + XCD grouping) -> y bf16
  attn_fwd<<<dim3(768, 1, 1), 256, 0, stream>>>(qh, kh, vh, y);
  // 4) output projection -> fp32 d_out
  gemm_proj<1><<<dim3(384, 1, 1), 256, 0, stream>>>(y, y, y, wwo, wwo, wwo, d_out, d_out, d_out);
}